// Round 10
// baseline (778.246 us; speedup 1.0000x reference)
//
#include <hip/hip_runtime.h>

#define NN 20000
#define NE 100000

typedef unsigned short u16;
typedef __bf16 bf16x8 __attribute__((ext_vector_type(8)));
typedef float f32x4 __attribute__((ext_vector_type(4)));
typedef short short8 __attribute__((ext_vector_type(8)));
typedef u16 u16x4 __attribute__((ext_vector_type(4)));

__device__ __forceinline__ float bf2f(u16 u) {
    union { unsigned int i; float f; } x; x.i = ((unsigned int)u) << 16; return x.f;
}
__device__ __forceinline__ u16 f2bf(float f) {
    union { float f; unsigned int i; } x; x.f = f;
    unsigned int r = x.i + 0x7FFFu + ((x.i >> 16) & 1u);
    return (u16)(r >> 16);
}

__device__ __forceinline__ void gl_lds16(const void* g, void* l) {
    __builtin_amdgcn_global_load_lds(
        (__attribute__((address_space(1))) const void*)g,
        (__attribute__((address_space(3))) void*)l, 16, 0, 0);
}

// bijective XCD-aware block swizzle (m204): each XCD gets a contiguous wgid range
__device__ __forceinline__ void xcd_swz(int& x, int& y) {
    int gx = gridDim.x;
    int nwg = gx * gridDim.y;
    int bid = blockIdx.y * gx + blockIdx.x;
    int q = nwg >> 3, r = nwg & 7;
    int xcd = bid & 7, idx = bid >> 3;
    int wg = (xcd < r ? xcd * (q + 1) : r * (q + 1) + (xcd - r) * q) + idx;
    x = wg % gx; y = wg / gx;
}

// ---------------- f32 -> bf16 bulk convert (4-wide) ----------------
__global__ void cvt_k(const float* __restrict__ in, u16* __restrict__ out, long n) {
    long i = ((long)blockIdx.x * 256 + threadIdx.x) * 4;
    if (i < n) {
        f32x4 v = *(const f32x4*)(in + i);
        u16x4 o;
        #pragma unroll
        for (int j = 0; j < 4; j++) o[j] = f2bf(v[j]);
        *(u16x4*)(out + i) = o;
    }
}

// ---------------- tiled transpose+convert: WT[n*Kr + k] = bf16(W[k*512 + n]) ----------------
__global__ __launch_bounds__(256)
void ttr_k(const float* __restrict__ W, u16* __restrict__ WT, int Kr) {
    __shared__ float tile[32][33];
    int k0 = blockIdx.x * 32, n0 = blockIdx.y * 32;
    int tx = threadIdx.x & 31, ty = threadIdx.x >> 5;   // 32 x 8
    #pragma unroll
    for (int i = 0; i < 4; i++)
        tile[ty + 8 * i][tx] = W[(size_t)(k0 + ty + 8 * i) * 512 + n0 + tx];
    __syncthreads();
    #pragma unroll
    for (int i = 0; i < 4; i++)
        WT[(size_t)(n0 + ty + 8 * i) * Kr + k0 + tx] = f2bf(tile[tx][ty + 8 * i]);
}

// ---------------- big GEMM: C[M,Nn] = A[M,K] @ WT^T (+bias), BM=128 BN=128 BK=64 ----------------
// XCD-swizzled grid. AK=0 plain (stride Ast); AK=2 [A|A2] K=1024.
// LOGIT: no C write; logits vs gathered q rows -> lgv (needs DEVM).
template<int AK, bool BIAS, bool DEVM, bool OUTF, bool LOGIT>
__global__ __launch_bounds__(256, 2)
void gemm_k(const u16* __restrict__ A, const u16* __restrict__ A2,
            const int* __restrict__ eids, const int* __restrict__ Be, int ci, int cap,
            const u16* __restrict__ WT, const float* __restrict__ bias,
            void* __restrict__ Cv,
            const u16* __restrict__ qbv, const int* __restrict__ dstv, float* __restrict__ lgv,
            int Mh, int K, int Ast, int Cst)
{
    __shared__ u16 smem[128 * 128];           // K-loop: sA | sB halves; LOGIT epilogue: q tile
    u16* sA = smem;
    u16* sB = smem + 128 * 64;
    int M = Mh, b0 = 0;
    if constexpr (DEVM) {
        b0 = Be[ci];
        M = min(Be[ci + 1] - b0, cap);
    }
    int bx, by;
    xcd_swz(bx, by);
    const int m0 = by * 128;
    if (m0 >= M) return;                    // uniform per block, before any barrier
    const int t = threadIdx.x;
    const int n0 = bx * 128;
    const int lane = t & 63;
    const int w = t >> 6;
    const int lrow = lane >> 3;             // 0..7 row within 8-row wave slab
    const int swz = ((lane & 7) ^ lrow) * 8;// pre-swizzled source chunk (elems)
    const int ldst = w * 512 + lane * 8;    // linear LDS dest (elems) within pass slab

    size_t abase[4];
    #pragma unroll
    for (int p = 0; p < 4; p++) {
        int row = min(m0 + p * 32 + w * 8 + lrow, M - 1);
        if constexpr (AK == 2) abase[p] = (size_t)row * 512;
        else                   abase[p] = (size_t)row * Ast;
    }
    const int wm = w >> 1, wn = w & 1;
    const int lm = lane & 15, lk = lane >> 4;
    const int swzr = lm & 7;                // row&7 for fragment-read deswizzle

    f32x4 acc[4][4] = {};

    for (int k0 = 0; k0 < K; k0 += 64) {
        #pragma unroll
        for (int p = 0; p < 4; p++) {
            const u16* g;
            if constexpr (AK == 2) {
                g = (k0 < 512) ? (A + abase[p] + k0 + swz) : (A2 + abase[p] + (k0 - 512) + swz);
            } else {
                g = A + abase[p] + k0 + swz;
            }
            gl_lds16(g, sA + p * 2048 + ldst);
        }
        #pragma unroll
        for (int p = 0; p < 4; p++)
            gl_lds16(WT + (size_t)(n0 + p * 32 + w * 8 + lrow) * K + k0 + swz, sB + p * 2048 + ldst);
        __syncthreads();

        bf16x8 av[2][4], bv[2][4];
        #pragma unroll
        for (int hf = 0; hf < 2; hf++) {
            #pragma unroll
            for (int mi = 0; mi < 4; mi++)
                av[hf][mi] = *(const bf16x8*)(sA + (wm * 64 + mi * 16 + lm) * 64 + (((hf * 4 + lk) ^ swzr) * 8));
            #pragma unroll
            for (int ni = 0; ni < 4; ni++)
                bv[hf][ni] = *(const bf16x8*)(sB + (wn * 64 + ni * 16 + lm) * 64 + (((hf * 4 + lk) ^ swzr) * 8));
        }
        #pragma unroll
        for (int hf = 0; hf < 2; hf++)
            #pragma unroll
            for (int mi = 0; mi < 4; mi++)
                #pragma unroll
                for (int ni = 0; ni < 4; ni++)
                    acc[mi][ni] = __builtin_amdgcn_mfma_f32_16x16x32_bf16(av[hf][mi], bv[hf][ni], acc[mi][ni], 0, 0, 0);
        __syncthreads();
    }

    float bvv[4];
    #pragma unroll
    for (int ni = 0; ni < 4; ni++) bvv[ni] = BIAS ? bias[n0 + wn * 64 + ni * 16 + lm] : 0.f;

    if constexpr (LOGIT) {
        // stage q[dst[e]] tile (128 rows x 128 cols, swizzled) into smem
        const int qrow = t >> 4;            // 0..15 within pass
        const int qc = t & 15;
        #pragma unroll
        for (int p = 0; p < 8; p++) {
            int row = p * 16 + qrow;
            int grow = min(m0 + row, M - 1);
            int e = eids[b0 + grow];
            const u16* g = qbv + (size_t)dstv[e] * 512 + n0 + ((qc ^ (row & 7)) << 3);
            gl_lds16(g, smem + p * 2048 + t * 8);
        }
        __syncthreads();
        #pragma unroll
        for (int mi = 0; mi < 4; mi++) {
            #pragma unroll
            for (int r = 0; r < 4; r++) {
                int rloc = wm * 64 + mi * 16 + lk * 4 + r;
                float h0 = 0.f, h1 = 0.f;
                #pragma unroll
                for (int ni = 0; ni < 4; ni++) {
                    int cloc = wn * 64 + ni * 16 + lm;
                    int addr = rloc * 128 + ((((cloc >> 3) ^ (rloc & 7)) << 3) | (cloc & 7));
                    float qv = bf2f(smem[addr]);
                    float pr = (acc[mi][ni][r] + bvv[ni]) * qv;
                    if (ni < 2) h0 += pr; else h1 += pr;
                }
                #pragma unroll
                for (int o = 1; o < 16; o <<= 1) { h0 += __shfl_xor(h0, o); h1 += __shfl_xor(h1, o); }
                int grow = m0 + rloc;
                if (lm == 0 && grow < M) {
                    int hbase = (n0 >> 5) + wn * 2;
                    lgv[(size_t)(b0 + grow) * 16 + hbase]     = h0 * 0.17677669529663687f;
                    lgv[(size_t)(b0 + grow) * 16 + hbase + 1] = h1 * 0.17677669529663687f;
                }
            }
        }
        return;
    }

    #pragma unroll
    for (int mi = 0; mi < 4; mi++) {
        int rbase = m0 + wm * 64 + mi * 16 + lk * 4;
        #pragma unroll
        for (int ni = 0; ni < 4; ni++) {
            int n = n0 + wn * 64 + ni * 16 + lm;
            #pragma unroll
            for (int r = 0; r < 4; r++) {
                int row = rbase + r;
                if (row < M) {
                    float cv = acc[mi][ni][r] + bvv[ni];
                    if constexpr (OUTF) ((float*)Cv)[(size_t)row * Cst + n] = cv;
                    else                ((u16*)Cv)[(size_t)row * Cst + n] = f2bf(cv);
                }
            }
        }
    }
}

// ---------------- small GEMM for node-side M=20000: BM=64 BN=128 BK=64, XCD-swizzled ----------------
template<int AK, bool BIAS, bool RES, bool OUTF, bool RESB>
__global__ __launch_bounds__(256, 3)
void gemmS_k(const u16* __restrict__ A, const u16* __restrict__ A2,
             const u16* __restrict__ WT, const float* __restrict__ bias,
             const float* __restrict__ resid, void* __restrict__ Cv,
             int M, int K, int Ast, int Cst)
{
    __shared__ u16 sA[64 * 64];
    __shared__ u16 sB[128 * 64];
    int bx, by;
    xcd_swz(bx, by);
    const int m0 = by * 64;
    if (m0 >= M) return;
    const int t = threadIdx.x;
    const int n0 = bx * 128;
    const int lane = t & 63;
    const int w = t >> 6;
    const int lrow = lane >> 3;
    const int swz = ((lane & 7) ^ lrow) * 8;
    const int ldst = w * 512 + lane * 8;

    size_t abase[2];
    #pragma unroll
    for (int p = 0; p < 2; p++) {
        int row = min(m0 + p * 32 + w * 8 + lrow, M - 1);
        if constexpr (AK == 2) abase[p] = (size_t)row * 512;
        else                   abase[p] = (size_t)row * Ast;
    }
    const int wm = w >> 1, wn = w & 1;
    const int lm = lane & 15, lk = lane >> 4;
    const int swzr = lm & 7;

    f32x4 acc[2][4] = {};

    for (int k0 = 0; k0 < K; k0 += 64) {
        #pragma unroll
        for (int p = 0; p < 2; p++) {
            const u16* g;
            if constexpr (AK == 2) {
                g = (k0 < 512) ? (A + abase[p] + k0 + swz) : (A2 + abase[p] + (k0 - 512) + swz);
            } else {
                g = A + abase[p] + k0 + swz;
            }
            gl_lds16(g, sA + p * 2048 + ldst);
        }
        #pragma unroll
        for (int p = 0; p < 4; p++)
            gl_lds16(WT + (size_t)(n0 + p * 32 + w * 8 + lrow) * K + k0 + swz, sB + p * 2048 + ldst);
        __syncthreads();

        bf16x8 av[2][2], bv[2][4];
        #pragma unroll
        for (int hf = 0; hf < 2; hf++) {
            #pragma unroll
            for (int mi = 0; mi < 2; mi++)
                av[hf][mi] = *(const bf16x8*)(sA + (wm * 32 + mi * 16 + lm) * 64 + (((hf * 4 + lk) ^ swzr) * 8));
            #pragma unroll
            for (int ni = 0; ni < 4; ni++)
                bv[hf][ni] = *(const bf16x8*)(sB + (wn * 64 + ni * 16 + lm) * 64 + (((hf * 4 + lk) ^ swzr) * 8));
        }
        #pragma unroll
        for (int hf = 0; hf < 2; hf++)
            #pragma unroll
            for (int mi = 0; mi < 2; mi++)
                #pragma unroll
                for (int ni = 0; ni < 4; ni++)
                    acc[mi][ni] = __builtin_amdgcn_mfma_f32_16x16x32_bf16(av[hf][mi], bv[hf][ni], acc[mi][ni], 0, 0, 0);
        __syncthreads();
    }

    float bvv[4];
    #pragma unroll
    for (int ni = 0; ni < 4; ni++) bvv[ni] = BIAS ? bias[n0 + wn * 64 + ni * 16 + lm] : 0.f;
    #pragma unroll
    for (int mi = 0; mi < 2; mi++) {
        int rbase = m0 + wm * 32 + mi * 16 + lk * 4;
        #pragma unroll
        for (int ni = 0; ni < 4; ni++) {
            int n = n0 + wn * 64 + ni * 16 + lm;
            #pragma unroll
            for (int r = 0; r < 4; r++) {
                int row = rbase + r;
                if (row < M) {
                    float cv = acc[mi][ni][r] + bvv[ni];
                    if constexpr (RES) {
                        if constexpr (RESB) cv += bf2f(((const u16*)resid)[(size_t)row * 512 + n]);
                        else                cv += resid[(size_t)row * 512 + n];
                    }
                    if constexpr (OUTF) ((float*)Cv)[(size_t)row * Cst + n] = cv;
                    else                ((u16*)Cv)[(size_t)row * Cst + n] = f2bf(cv);
                }
            }
        }
    }
}

// ---------------- fused edge GEMM1 + NP-gather + b1 + LN*g+be + ReLU -> hidC (v2 + T14 gather prefetch) ----------------
// 512 threads / 8 waves. BM=64 edges, N=512 full, K=128 (BK=32).
// NP rows for the epilogue are prefetched into registers BEFORE the K-loop (latency hides under staging+MFMA).
__global__ __launch_bounds__(512, 4)
void g1ln_k(const u16* __restrict__ efb, const u16* __restrict__ WTe,
            const u16* __restrict__ NPp, const int* __restrict__ eids, const int* __restrict__ srcv,
            const int* __restrict__ Be, int ci, int cap,
            const float* __restrict__ b1, const float* __restrict__ g, const float* __restrict__ be,
            u16* __restrict__ outb)
{
    __shared__ u16 lds[32768];             // 64 KB: A 16KB | B 32KB during K-loop; f32 C 32x512 in epilogue
    u16* sA = lds;                         // [64][128] swizzled
    u16* sB = lds + 8192;                  // [512][32] swizzled
    float* sC = (float*)lds;               // [32][512] swizzled (epilogue only)
    int b0 = Be[ci];
    int M = min(Be[ci + 1] - b0, cap);
    const int m0 = blockIdx.x * 64;
    if (m0 >= M) return;
    const int t = threadIdx.x;
    const int lane = t & 63;
    const int w = t >> 6;                  // 8 waves; wave owns col slice w*64
    const int lm = lane & 15, lk = lane >> 4;

    // ---- T14: prefetch NP rows this thread will need in the epilogue (8 rows, 32 VGPRs)
    short8 gvreg[2][4];
    #pragma unroll
    for (int half = 0; half < 2; half++)
        #pragma unroll
        for (int i = 0; i < 4; i++) {
            int row_g = m0 + half * 32 + w * 4 + i;
            int rc = min(row_g, M - 1);
            int eid = eids[b0 + rc];
            gvreg[half][i] = *(const short8*)(NPp + (size_t)srcv[eid] * 1536 + lane * 8);
        }
    // hoist per-lane LN params
    float b1r[8], gr[8], ber[8];
    #pragma unroll
    for (int j = 0; j < 8; j++) { b1r[j] = b1[lane * 8 + j]; gr[j] = g[lane * 8 + j]; ber[j] = be[lane * 8 + j]; }

    // stage whole A (64 rows x 128 k, ef gather, granule-swizzled): 1024 granules, 2/thread
    #pragma unroll
    for (int p = 0; p < 2; p++) {
        int slot = p * 512 + t;
        int row = slot >> 4, gph = slot & 15;
        int gsrc = (gph & 8) | ((gph & 7) ^ (row & 7));
        int eid = eids[b0 + min(m0 + row, M - 1)];
        gl_lds16(efb + (size_t)eid * 128 + gsrc * 8, sA + slot * 8);
    }

    f32x4 acc[4][4] = {};
    for (int ks = 0; ks < 4; ks++) {
        // stage B slice (512 n x 32 k): 2048 granules, 4/thread; 4-granule XOR by n&3
        #pragma unroll
        for (int p = 0; p < 4; p++) {
            int slot = p * 512 + t;
            int n = slot >> 2, cph = slot & 3;
            int csrc = cph ^ (n & 3);
            gl_lds16(WTe + (size_t)n * 128 + ks * 32 + csrc * 8, sB + slot * 8);
        }
        __syncthreads();
        bf16x8 av[4], bv[4];
        #pragma unroll
        for (int mi = 0; mi < 4; mi++) {
            int row = mi * 16 + lm;
            int gl = ks * 4 + lk;
            int gph = (gl & 8) | ((gl & 7) ^ (row & 7));
            av[mi] = *(const bf16x8*)(sA + row * 128 + gph * 8);
        }
        #pragma unroll
        for (int ni = 0; ni < 4; ni++) {
            int n = w * 64 + ni * 16 + lm;
            bv[ni] = *(const bf16x8*)(sB + n * 32 + (lk ^ (n & 3)) * 8);
        }
        #pragma unroll
        for (int mi = 0; mi < 4; mi++)
            #pragma unroll
            for (int ni = 0; ni < 4; ni++)
                acc[mi][ni] = __builtin_amdgcn_mfma_f32_16x16x32_bf16(av[mi], bv[ni], acc[mi][ni], 0, 0, 0);
        __syncthreads();
    }

    // epilogue: two 32-row halves through f32 LDS (granule-of-4 XOR swizzle by row&7)
    for (int half = 0; half < 2; half++) {
        #pragma unroll
        for (int mi2 = 0; mi2 < 2; mi2++) {
            int mi = half * 2 + mi2;
            #pragma unroll
            for (int ni = 0; ni < 4; ni++) {
                int col = w * 64 + ni * 16 + lm;
                int c4 = col >> 2;
                #pragma unroll
                for (int r = 0; r < 4; r++) {
                    int row_l = mi2 * 16 + lk * 4 + r;
                    int ph4 = (c4 & ~7) | ((c4 & 7) ^ (row_l & 7));
                    sC[row_l * 512 + ph4 * 4 + (col & 3)] = acc[mi][ni][r];
                }
            }
        }
        __syncthreads();
        #pragma unroll
        for (int i = 0; i < 4; i++) {
            int row_l = w * 4 + i;
            int row_g = m0 + half * 32 + row_l;
            if (row_g < M) {
                int g0 = lane * 2, g1 = g0 + 1;
                int p0 = (g0 & ~7) | ((g0 & 7) ^ (row_l & 7));
                int p1 = (g1 & ~7) | ((g1 & 7) ^ (row_l & 7));
                f32x4 ca = *(const f32x4*)(sC + row_l * 512 + p0 * 4);
                f32x4 cb = *(const f32x4*)(sC + row_l * 512 + p1 * 4);
                short8 gv = gvreg[half][i];
                float x[8]; float s = 0.f, s2 = 0.f;
                #pragma unroll
                for (int j = 0; j < 4; j++) x[j] = ca[j] + bf2f((u16)gv[j]) + b1r[j];
                #pragma unroll
                for (int j = 4; j < 8; j++) x[j] = cb[j - 4] + bf2f((u16)gv[j]) + b1r[j];
                #pragma unroll
                for (int j = 0; j < 8; j++) { s += x[j]; s2 += x[j] * x[j]; }
                #pragma unroll
                for (int o = 32; o > 0; o >>= 1) { s += __shfl_xor(s, o); s2 += __shfl_xor(s2, o); }
                float mu = s * (1.f / 512.f);
                float inv = rsqrtf(s2 * (1.f / 512.f) - mu * mu + 1e-5f);
                short8 ov;
                #pragma unroll
                for (int j = 0; j < 8; j++) {
                    float y = (x[j] - mu) * inv * gr[j] + ber[j];
                    ov[j] = (short)f2bf(fmaxf(y, 0.f));
                }
                *(short8*)(outb + (size_t)row_g * 512 + lane * 8) = ov;
            }
        }
        __syncthreads();
    }
}

// ---------------- (x + b1) -> LayerNorm*g+be -> ReLU, in place, wave per row ----------------
__global__ __launch_bounds__(256)
void ln_relu_k(u16* __restrict__ hid, int hst,
               const float* __restrict__ b1, const float* __restrict__ g, const float* __restrict__ be,
               int M) {
    int wid = threadIdx.x >> 6, lane = threadIdx.x & 63;
    long r = (long)blockIdx.x * 4 + wid;
    if (r >= M) return;
    u16* p = hid + r * hst + lane * 8;
    short8 v = *(const short8*)p;
    float x[8]; float s = 0.f, s2 = 0.f;
    #pragma unroll
    for (int j = 0; j < 8; j++) x[j] = bf2f((u16)v[j]) + b1[lane * 8 + j];
    #pragma unroll
    for (int j = 0; j < 8; j++) { s += x[j]; s2 += x[j] * x[j]; }
    #pragma unroll
    for (int o = 32; o > 0; o >>= 1) { s += __shfl_xor(s, o); s2 += __shfl_xor(s2, o); }
    float mu = s * (1.f / 512.f);
    float inv = rsqrtf(s2 * (1.f / 512.f) - mu * mu + 1e-5f);
    short8 ov;
    #pragma unroll
    for (int j = 0; j < 8; j++) {
        float y = (x[j] - mu) * inv * g[lane * 8 + j] + be[lane * 8 + j];
        ov[j] = (short)f2bf(fmaxf(y, 0.f));
    }
    *(short8*)p = ov;
}

// ---------------- CSR build ----------------
__global__ void zero_k(int* a, int n) { int i = blockIdx.x * 256 + threadIdx.x; if (i < n) a[i] = 0; }
__global__ void count_k(const int* __restrict__ dst, int* __restrict__ counts) {
    int i = blockIdx.x * 256 + threadIdx.x;
    if (i < NE) atomicAdd(&counts[dst[i]], 1);
}
__global__ __launch_bounds__(1024)
void scan_k(const int* __restrict__ counts, int* __restrict__ offs) {
    __shared__ int part[1024];
    int t = threadIdx.x;
    const int chunk = (NN + 1023) / 1024;
    int lo = t * chunk; if (lo > NN) lo = NN;
    int hi = lo + chunk; if (hi > NN) hi = NN;
    int s = 0;
    for (int i = lo; i < hi; i++) s += counts[i];
    part[t] = s;
    __syncthreads();
    for (int o = 1; o < 1024; o <<= 1) {
        int v2 = 0;
        if (t >= o) v2 = part[t - o];
        __syncthreads();
        part[t] += v2;
        __syncthreads();
    }
    int base = (t > 0) ? part[t - 1] : 0;
    for (int i = lo; i < hi; i++) { offs[i] = base; base += counts[i]; }
    if (t == 1023) offs[NN] = part[1023];
}
__global__ void scatter_k(const int* __restrict__ dst, const int* __restrict__ offs,
                          int* __restrict__ cur, int* __restrict__ eids) {
    int i = blockIdx.x * 256 + threadIdx.x;
    if (i < NE) {
        int d = dst[i];
        int pos = atomicAdd(&cur[d], 1);
        eids[offs[d] + pos] = i;
    }
}
__global__ void bounds_k(const int* __restrict__ offs, int* __restrict__ Pn, int* __restrict__ Be,
                         int NC, int CEt) {
    int c = threadIdx.x;
    if (c > NC) return;
    int n;
    if (c == 0) n = 0;
    else if (c == NC) n = NN;
    else {
        int target = c * CEt;
        int lo = 0, hi = NN;
        while (lo < hi) { int mid = (lo + hi + 1) >> 1; if (offs[mid] <= target) lo = mid; else hi = mid - 1; }
        n = lo;
    }
    Pn[c] = n; Be[c] = offs[n];
}

// ---------------- per-node softmax stats over full logit array ----------------
__global__ __launch_bounds__(256)
void mxden_k(const float* __restrict__ lg, const int* __restrict__ offs,
             float* __restrict__ mx, float* __restrict__ den) {
    int wid = threadIdx.x >> 6, lane = threadIdx.x & 63;
    int n = blockIdx.x * 4 + wid;
    if (n >= NN) return;
    int lo = offs[n], hi = offs[n + 1];
    int head = lane & 15, j = lane >> 4;
    float m = -1e30f;
    for (int pe = lo + j; pe < hi; pe += 4)
        m = fmaxf(m, lg[(long)pe * 16 + head]);
    m = fmaxf(m, __shfl_xor(m, 16));
    m = fmaxf(m, __shfl_xor(m, 32));
    float d = 0.f;
    for (int pe = lo + j; pe < hi; pe += 4)
        d += __expf(lg[(long)pe * 16 + head] - m);
    d += __shfl_xor(d, 16);
    d += __shfl_xor(d, 32);
    if (j == 0) { mx[n * 16 + head] = m; den[n * 16 + head] = d; }
}

// ---------------- weighted V aggregation for nodes inside chunk ci, wave per node ----------------
__global__ __launch_bounds__(256)
void aggc_k(const float* __restrict__ lg, const u16* __restrict__ v,
            const int* __restrict__ offs, const float* __restrict__ mx, const float* __restrict__ den,
            const int* __restrict__ Pn, const int* __restrict__ Be, int ci, int cap,
            u16* __restrict__ agg) {
    int wid = threadIdx.x >> 6, lane = threadIdx.x & 63;
    int n = blockIdx.x * 4 + wid;
    if (n >= NN) return;
    if (n < Pn[ci] || n >= Pn[ci + 1]) return;
    int lo = offs[n], hi = offs[n + 1], b0 = Be[ci];
    int head = lane >> 2;
    float m = mx[n * 16 + head];
    float dv = den[n * 16 + head];
    float rn = (hi > lo) ? (1.f / dv) : 0.f;
    float acc[8] = {0, 0, 0, 0, 0, 0, 0, 0};
    for (int pe = lo; pe < hi; pe++) {
        int r = pe - b0;
        if (r >= cap) break;
        float wgt = __expf(lg[(long)pe * 16 + head] - m);
        short8 vv = *(const short8*)(v + (long)r * 512 + lane * 8);
        #pragma unroll
        for (int j = 0; j < 8; j++) acc[j] += wgt * bf2f((u16)vv[j]);
    }
    short8 ov;
    #pragma unroll
    for (int j = 0; j < 8; j++) ov[j] = (short)f2bf(acc[j] * rn);
    *(short8*)(agg + (long)n * 512 + lane * 8) = ov;
}

extern "C" void kernel_launch(void* const* d_in, const int* in_sizes, int n_in,
                              void* d_out, int out_size, void* d_ws, size_t ws_size,
                              hipStream_t stream) {
    const float* h     = (const float*)d_in[0];
    const float* efeat = (const float*)d_in[1];
    const int*   eidx  = (const int*)d_in[2];
    const int* src = eidx;
    const int* dst = eidx + NE;
    const float* hkW1 = (const float*)d_in[3];  const float* hkb1 = (const float*)d_in[4];
    const float* hkg  = (const float*)d_in[5];  const float* hkbe = (const float*)d_in[6];
    const float* hkW2 = (const float*)d_in[7];  const float* hkb2 = (const float*)d_in[8];
    const float* hvW1 = (const float*)d_in[9];  const float* hvb1 = (const float*)d_in[10];
    const float* hvg  = (const float*)d_in[11]; const float* hvbe = (const float*)d_in[12];
    const float* hvW2 = (const float*)d_in[13]; const float* hvb2 = (const float*)d_in[14];
    const float* hqW1 = (const float*)d_in[15]; const float* hqb1 = (const float*)d_in[16];
    const float* hqg  = (const float*)d_in[17]; const float* hqbe = (const float*)d_in[18];
    const float* hqW2 = (const float*)d_in[19]; const float* hqb2 = (const float*)d_in[20];
    const float* noW1 = (const float*)d_in[21]; const float* nob1 = (const float*)d_in[22];
    const float* nog  = (const float*)d_in[23]; const float* nobe = (const float*)d_in[24];
    const float* noW2 = (const float*)d_in[25]; const float* nob2 = (const float*)d_in[26];
    (void)in_sizes; (void)n_in; (void)out_size;

    char* wsp = (char*)d_ws;
    auto take = [&](size_t b) -> char* {
        char* r = wsp; wsp += (b + 255) & ~(size_t)255; return r;
    };
    u16* hb    = (u16*)take((size_t)NN * 512 * 2);
    u16* efb   = (u16*)take((size_t)NE * 128 * 2);
    u16* qb    = (u16*)take((size_t)NN * 512 * 2);    // q; reused as final-MLP hidden
    u16* aggb  = (u16*)take((size_t)NN * 512 * 2);
    u16* NP    = (u16*)take((size_t)NN * 1536 * 2);   // [q-hid | k-part | v-part] per node
    float* lgb = (float*)take((size_t)NE * 16 * 4);
    float* mxb = (float*)take((size_t)NN * 16 * 4);
    float* denb= (float*)take((size_t)NN * 16 * 4);
    u16* WTn    = (u16*)take((size_t)1536 * 512 * 2); // stacked [hqW1T | hkW1Th | hvW1Th]
    u16* noW1T  = (u16*)take(512 * 1024 * 2);
    u16* hkW1Te = (u16*)take(512 * 128 * 2);
    u16* hvW1Te = (u16*)take(512 * 128 * 2);
    u16* hkW2T  = (u16*)take(512 * 512 * 2);
    u16* hvW2T  = (u16*)take(512 * 512 * 2);
    u16* hqW2T  = (u16*)take(512 * 512 * 2);
    u16* noW2T  = (u16*)take(512 * 512 * 2);
    int* counts = (int*)take(NN * 4);
    int* offs   = (int*)take((NN + 1) * 4);
    int* cur    = (int*)take(NN * 4);
    int* eids   = (int*)take(NE * 4);
    int* Pn     = (int*)take(64 * 4);
    int* Bed    = (int*)take(64 * 4);

    size_t base = (size_t)(wsp - (char*)d_ws);
    const int ncs[15] = {1, 2, 3, 4, 5, 6, 8, 10, 13, 16, 20, 25, 32, 40, 50};
    int NC = 50;
    size_t cap = (size_t)((NE + 49) / 50) + 2048;
    for (int i = 0; i < 15; i++) {
        int nc = ncs[i];
        int cet = (NE + nc - 1) / nc;
        size_t c2 = (nc == 1) ? (size_t)NE : (size_t)cet + 2048;
        size_t buf = (c2 * 1024 + 255) & ~(size_t)255;
        if (base + 2 * buf <= ws_size) { NC = nc; cap = c2; break; }
    }
    size_t chunkbuf = (cap * 1024 + 255) & ~(size_t)255;
    u16* hidC = (u16*)take(chunkbuf);
    u16* kvC  = (u16*)take(chunkbuf);
    const int icap = (int)cap;
    const int CEt = (NE + NC - 1) / NC;

    cvt_k<<<((NN * 512 / 4) + 255) / 256, 256, 0, stream>>>(h, hb, (long)NN * 512);
    cvt_k<<<((NE * 128 / 4) + 255) / 256, 256, 0, stream>>>(efeat, efb, (long)NE * 128);

    dim3 tb(256);
    ttr_k<<<dim3(16, 16), tb, 0, stream>>>(hqW1, WTn, 512);
    ttr_k<<<dim3(16, 16), tb, 0, stream>>>(hkW1, WTn + 512 * 512, 512);
    ttr_k<<<dim3(16, 16), tb, 0, stream>>>(hvW1, WTn + 2 * 512 * 512, 512);
    ttr_k<<<dim3(4, 16),  tb, 0, stream>>>(hkW1 + 512 * 512, hkW1Te, 128);
    ttr_k<<<dim3(4, 16),  tb, 0, stream>>>(hvW1 + 512 * 512, hvW1Te, 128);
    ttr_k<<<dim3(32, 16), tb, 0, stream>>>(noW1, noW1T, 1024);
    ttr_k<<<dim3(16, 16), tb, 0, stream>>>(hkW2, hkW2T, 512);
    ttr_k<<<dim3(16, 16), tb, 0, stream>>>(hvW2, hvW2T, 512);
    ttr_k<<<dim3(16, 16), tb, 0, stream>>>(hqW2, hqW2T, 512);
    ttr_k<<<dim3(16, 16), tb, 0, stream>>>(noW2, noW2T, 512);

    zero_k<<<(NN + 255) / 256, 256, 0, stream>>>(counts, NN);
    zero_k<<<(NN + 255) / 256, 256, 0, stream>>>(cur, NN);
    count_k<<<(NE + 255) / 256, 256, 0, stream>>>(dst, counts);
    scan_k<<<1, 1024, 0, stream>>>(counts, offs);
    scatter_k<<<(NE + 255) / 256, 256, 0, stream>>>(dst, offs, cur, eids);
    bounds_k<<<1, 64, 0, stream>>>(offs, Pn, Bed, NC, CEt);

    dim3 gNP(12, (NN + 127) / 128);
    dim3 gNS(4, (NN + 63) / 64);
    dim3 gC(4, ((int)cap + 127) / 128);
    int lnN = (NN + 3) / 4;
    int g1b = ((int)cap + 63) / 64;

    // ---- fused node-side W1 GEMM: NP[20000,1536] = hb @ [hqW1 | hkW1h | hvW1h]
    gemm_k<0, false, false, false, false><<<gNP, 256, 0, stream>>>(
        hb, nullptr, nullptr, nullptr, 0, 0, WTn, nullptr, NP,
        nullptr, nullptr, nullptr, NN, 512, 512, 1536);

    // ---- q MLP tail
    ln_relu_k<<<lnN, 256, 0, stream>>>(NP, 1536, hqb1, hqg, hqbe, NN);
    gemmS_k<0, true, false, false, false><<<gNS, 256, 0, stream>>>(NP, nullptr, hqW2T, hqb2, nullptr, qb,
                                                                   NN, 512, 1536, 512);

    // ---- K phase: fused g1ln -> hidC; GEMM2+logits fused
    for (int c = 0; c < NC; c++) {
        g1ln_k<<<g1b, 512, 0, stream>>>(efb, hkW1Te, NP + 512, eids, src, Bed, c, icap,
                                        hkb1, hkg, hkbe, hidC);
        gemm_k<0, true, true, false, true><<<gC, 256, 0, stream>>>(
            hidC, nullptr, eids, Bed, c, icap, hkW2T, hkb2, nullptr,
            qb, dst, lgb, 0, 512, 512, 512);
    }

    mxden_k<<<lnN, 256, 0, stream>>>(lgb, offs, mxb, denb);

    // ---- V phase: fused g1ln -> hidC; v -> kvC; aggregate
    for (int c = 0; c < NC; c++) {
        g1ln_k<<<g1b, 512, 0, stream>>>(efb, hvW1Te, NP + 1024, eids, src, Bed, c, icap,
                                        hvb1, hvg, hvbe, hidC);
        gemm_k<0, true, true, false, false><<<gC, 256, 0, stream>>>(
            hidC, nullptr, nullptr, Bed, c, icap, hvW2T, hvb2, kvC,
            nullptr, nullptr, nullptr, 0, 512, 512, 512);
        aggc_k<<<lnN, 256, 0, stream>>>(lgb, kvC, offs, mxb, denb, Pn, Bed, c, icap, aggb);
    }

    // ---- node output MLP (concat A) + bf16 residual, f32 into d_out
    gemmS_k<2, false, false, false, false><<<gNS, 256, 0, stream>>>(aggb, hb, noW1T, nullptr, nullptr, qb,
                                                                    NN, 1024, 512, 512);
    ln_relu_k<<<lnN, 256, 0, stream>>>(qb, 512, nob1, nog, nobe, NN);
    gemmS_k<0, true, true, true, true><<<gNS, 256, 0, stream>>>(qb, nullptr, noW2T, nob2, (const float*)hb, d_out,
                                                                NN, 512, 512, 512);
}

// Round 11
// 714.587 us; speedup vs baseline: 1.0891x; 1.0891x over previous
//
#include <hip/hip_runtime.h>

#define NN 20000
#define NE 100000

typedef unsigned short u16;
typedef __bf16 bf16x8 __attribute__((ext_vector_type(8)));
typedef float f32x4 __attribute__((ext_vector_type(4)));
typedef short short8 __attribute__((ext_vector_type(8)));
typedef u16 u16x4 __attribute__((ext_vector_type(4)));

__device__ __forceinline__ float bf2f(u16 u) {
    union { unsigned int i; float f; } x; x.i = ((unsigned int)u) << 16; return x.f;
}
__device__ __forceinline__ u16 f2bf(float f) {
    union { float f; unsigned int i; } x; x.f = f;
    unsigned int r = x.i + 0x7FFFu + ((x.i >> 16) & 1u);
    return (u16)(r >> 16);
}

__device__ __forceinline__ void gl_lds16(const void* g, void* l) {
    __builtin_amdgcn_global_load_lds(
        (__attribute__((address_space(1))) const void*)g,
        (__attribute__((address_space(3))) void*)l, 16, 0, 0);
}

// bijective XCD-aware block swizzle (m204): each XCD gets a contiguous wgid range
__device__ __forceinline__ void xcd_swz(int& x, int& y) {
    int gx = gridDim.x;
    int nwg = gx * gridDim.y;
    int bid = blockIdx.y * gx + blockIdx.x;
    int q = nwg >> 3, r = nwg & 7;
    int xcd = bid & 7, idx = bid >> 3;
    int wg = (xcd < r ? xcd * (q + 1) : r * (q + 1) + (xcd - r) * q) + idx;
    x = wg % gx; y = wg / gx;
}

// ---------------- f32 -> bf16 bulk convert (4-wide) ----------------
__global__ void cvt_k(const float* __restrict__ in, u16* __restrict__ out, long n) {
    long i = ((long)blockIdx.x * 256 + threadIdx.x) * 4;
    if (i < n) {
        f32x4 v = *(const f32x4*)(in + i);
        u16x4 o;
        #pragma unroll
        for (int j = 0; j < 4; j++) o[j] = f2bf(v[j]);
        *(u16x4*)(out + i) = o;
    }
}

// ---------------- tiled transpose+convert: WT[n*Kr + k] = bf16(W[k*512 + n]) ----------------
__global__ __launch_bounds__(256)
void ttr_k(const float* __restrict__ W, u16* __restrict__ WT, int Kr) {
    __shared__ float tile[32][33];
    int k0 = blockIdx.x * 32, n0 = blockIdx.y * 32;
    int tx = threadIdx.x & 31, ty = threadIdx.x >> 5;   // 32 x 8
    #pragma unroll
    for (int i = 0; i < 4; i++)
        tile[ty + 8 * i][tx] = W[(size_t)(k0 + ty + 8 * i) * 512 + n0 + tx];
    __syncthreads();
    #pragma unroll
    for (int i = 0; i < 4; i++)
        WT[(size_t)(n0 + ty + 8 * i) * Kr + k0 + tx] = f2bf(tile[tx][ty + 8 * i]);
}

// ---------------- big GEMM: C[M,Nn] = A[M,K] @ WT^T (+bias), BM=128 BN=128 BK=64 ----------------
// XCD-swizzled grid. AK=0 plain (stride Ast); AK=2 [A|A2] K=1024.
// LOGIT: no C write; logits vs gathered q rows -> lgv (needs DEVM).
template<int AK, bool BIAS, bool DEVM, bool OUTF, bool LOGIT>
__global__ __launch_bounds__(256, 2)
void gemm_k(const u16* __restrict__ A, const u16* __restrict__ A2,
            const int* __restrict__ eids, const int* __restrict__ Be, int ci, int cap,
            const u16* __restrict__ WT, const float* __restrict__ bias,
            void* __restrict__ Cv,
            const u16* __restrict__ qbv, const int* __restrict__ dstv, float* __restrict__ lgv,
            int Mh, int K, int Ast, int Cst)
{
    __shared__ u16 smem[128 * 128];           // K-loop: sA | sB halves; LOGIT epilogue: q tile
    u16* sA = smem;
    u16* sB = smem + 128 * 64;
    int M = Mh, b0 = 0;
    if constexpr (DEVM) {
        b0 = Be[ci];
        M = min(Be[ci + 1] - b0, cap);
    }
    int bx, by;
    xcd_swz(bx, by);
    const int m0 = by * 128;
    if (m0 >= M) return;                    // uniform per block, before any barrier
    const int t = threadIdx.x;
    const int n0 = bx * 128;
    const int lane = t & 63;
    const int w = t >> 6;
    const int lrow = lane >> 3;             // 0..7 row within 8-row wave slab
    const int swz = ((lane & 7) ^ lrow) * 8;// pre-swizzled source chunk (elems)
    const int ldst = w * 512 + lane * 8;    // linear LDS dest (elems) within pass slab

    size_t abase[4];
    #pragma unroll
    for (int p = 0; p < 4; p++) {
        int row = min(m0 + p * 32 + w * 8 + lrow, M - 1);
        if constexpr (AK == 2) abase[p] = (size_t)row * 512;
        else                   abase[p] = (size_t)row * Ast;
    }
    const int wm = w >> 1, wn = w & 1;
    const int lm = lane & 15, lk = lane >> 4;
    const int swzr = lm & 7;                // row&7 for fragment-read deswizzle

    f32x4 acc[4][4] = {};

    for (int k0 = 0; k0 < K; k0 += 64) {
        #pragma unroll
        for (int p = 0; p < 4; p++) {
            const u16* g;
            if constexpr (AK == 2) {
                g = (k0 < 512) ? (A + abase[p] + k0 + swz) : (A2 + abase[p] + (k0 - 512) + swz);
            } else {
                g = A + abase[p] + k0 + swz;
            }
            gl_lds16(g, sA + p * 2048 + ldst);
        }
        #pragma unroll
        for (int p = 0; p < 4; p++)
            gl_lds16(WT + (size_t)(n0 + p * 32 + w * 8 + lrow) * K + k0 + swz, sB + p * 2048 + ldst);
        __syncthreads();

        bf16x8 av[2][4], bv[2][4];
        #pragma unroll
        for (int hf = 0; hf < 2; hf++) {
            #pragma unroll
            for (int mi = 0; mi < 4; mi++)
                av[hf][mi] = *(const bf16x8*)(sA + (wm * 64 + mi * 16 + lm) * 64 + (((hf * 4 + lk) ^ swzr) * 8));
            #pragma unroll
            for (int ni = 0; ni < 4; ni++)
                bv[hf][ni] = *(const bf16x8*)(sB + (wn * 64 + ni * 16 + lm) * 64 + (((hf * 4 + lk) ^ swzr) * 8));
        }
        #pragma unroll
        for (int hf = 0; hf < 2; hf++)
            #pragma unroll
            for (int mi = 0; mi < 4; mi++)
                #pragma unroll
                for (int ni = 0; ni < 4; ni++)
                    acc[mi][ni] = __builtin_amdgcn_mfma_f32_16x16x32_bf16(av[hf][mi], bv[hf][ni], acc[mi][ni], 0, 0, 0);
        __syncthreads();
    }

    float bvv[4];
    #pragma unroll
    for (int ni = 0; ni < 4; ni++) bvv[ni] = BIAS ? bias[n0 + wn * 64 + ni * 16 + lm] : 0.f;

    if constexpr (LOGIT) {
        // stage q[dst[e]] tile (128 rows x 128 cols, swizzled) into smem
        const int qrow = t >> 4;            // 0..15 within pass
        const int qc = t & 15;
        #pragma unroll
        for (int p = 0; p < 8; p++) {
            int row = p * 16 + qrow;
            int grow = min(m0 + row, M - 1);
            int e = eids[b0 + grow];
            const u16* g = qbv + (size_t)dstv[e] * 512 + n0 + ((qc ^ (row & 7)) << 3);
            gl_lds16(g, smem + p * 2048 + t * 8);
        }
        __syncthreads();
        #pragma unroll
        for (int mi = 0; mi < 4; mi++) {
            #pragma unroll
            for (int r = 0; r < 4; r++) {
                int rloc = wm * 64 + mi * 16 + lk * 4 + r;
                float h0 = 0.f, h1 = 0.f;
                #pragma unroll
                for (int ni = 0; ni < 4; ni++) {
                    int cloc = wn * 64 + ni * 16 + lm;
                    int addr = rloc * 128 + ((((cloc >> 3) ^ (rloc & 7)) << 3) | (cloc & 7));
                    float qv = bf2f(smem[addr]);
                    float pr = (acc[mi][ni][r] + bvv[ni]) * qv;
                    if (ni < 2) h0 += pr; else h1 += pr;
                }
                #pragma unroll
                for (int o = 1; o < 16; o <<= 1) { h0 += __shfl_xor(h0, o); h1 += __shfl_xor(h1, o); }
                int grow = m0 + rloc;
                if (lm == 0 && grow < M) {
                    int hbase = (n0 >> 5) + wn * 2;
                    lgv[(size_t)(b0 + grow) * 16 + hbase]     = h0 * 0.17677669529663687f;
                    lgv[(size_t)(b0 + grow) * 16 + hbase + 1] = h1 * 0.17677669529663687f;
                }
            }
        }
        return;
    }

    #pragma unroll
    for (int mi = 0; mi < 4; mi++) {
        int rbase = m0 + wm * 64 + mi * 16 + lk * 4;
        #pragma unroll
        for (int ni = 0; ni < 4; ni++) {
            int n = n0 + wn * 64 + ni * 16 + lm;
            #pragma unroll
            for (int r = 0; r < 4; r++) {
                int row = rbase + r;
                if (row < M) {
                    float cv = acc[mi][ni][r] + bvv[ni];
                    if constexpr (OUTF) ((float*)Cv)[(size_t)row * Cst + n] = cv;
                    else                ((u16*)Cv)[(size_t)row * Cst + n] = f2bf(cv);
                }
            }
        }
    }
}

// ---------------- small GEMM for node-side M=20000: BM=64 BN=128 BK=64, XCD-swizzled ----------------
template<int AK, bool BIAS, bool RES, bool OUTF, bool RESB>
__global__ __launch_bounds__(256, 3)
void gemmS_k(const u16* __restrict__ A, const u16* __restrict__ A2,
             const u16* __restrict__ WT, const float* __restrict__ bias,
             const float* __restrict__ resid, void* __restrict__ Cv,
             int M, int K, int Ast, int Cst)
{
    __shared__ u16 sA[64 * 64];
    __shared__ u16 sB[128 * 64];
    int bx, by;
    xcd_swz(bx, by);
    const int m0 = by * 64;
    if (m0 >= M) return;
    const int t = threadIdx.x;
    const int n0 = bx * 128;
    const int lane = t & 63;
    const int w = t >> 6;
    const int lrow = lane >> 3;
    const int swz = ((lane & 7) ^ lrow) * 8;
    const int ldst = w * 512 + lane * 8;

    size_t abase[2];
    #pragma unroll
    for (int p = 0; p < 2; p++) {
        int row = min(m0 + p * 32 + w * 8 + lrow, M - 1);
        if constexpr (AK == 2) abase[p] = (size_t)row * 512;
        else                   abase[p] = (size_t)row * Ast;
    }
    const int wm = w >> 1, wn = w & 1;
    const int lm = lane & 15, lk = lane >> 4;
    const int swzr = lm & 7;

    f32x4 acc[2][4] = {};

    for (int k0 = 0; k0 < K; k0 += 64) {
        #pragma unroll
        for (int p = 0; p < 2; p++) {
            const u16* g;
            if constexpr (AK == 2) {
                g = (k0 < 512) ? (A + abase[p] + k0 + swz) : (A2 + abase[p] + (k0 - 512) + swz);
            } else {
                g = A + abase[p] + k0 + swz;
            }
            gl_lds16(g, sA + p * 2048 + ldst);
        }
        #pragma unroll
        for (int p = 0; p < 4; p++)
            gl_lds16(WT + (size_t)(n0 + p * 32 + w * 8 + lrow) * K + k0 + swz, sB + p * 2048 + ldst);
        __syncthreads();

        bf16x8 av[2][2], bv[2][4];
        #pragma unroll
        for (int hf = 0; hf < 2; hf++) {
            #pragma unroll
            for (int mi = 0; mi < 2; mi++)
                av[hf][mi] = *(const bf16x8*)(sA + (wm * 32 + mi * 16 + lm) * 64 + (((hf * 4 + lk) ^ swzr) * 8));
            #pragma unroll
            for (int ni = 0; ni < 4; ni++)
                bv[hf][ni] = *(const bf16x8*)(sB + (wn * 64 + ni * 16 + lm) * 64 + (((hf * 4 + lk) ^ swzr) * 8));
        }
        #pragma unroll
        for (int hf = 0; hf < 2; hf++)
            #pragma unroll
            for (int mi = 0; mi < 2; mi++)
                #pragma unroll
                for (int ni = 0; ni < 4; ni++)
                    acc[mi][ni] = __builtin_amdgcn_mfma_f32_16x16x32_bf16(av[hf][mi], bv[hf][ni], acc[mi][ni], 0, 0, 0);
        __syncthreads();
    }

    float bvv[4];
    #pragma unroll
    for (int ni = 0; ni < 4; ni++) bvv[ni] = BIAS ? bias[n0 + wn * 64 + ni * 16 + lm] : 0.f;
    #pragma unroll
    for (int mi = 0; mi < 2; mi++) {
        int rbase = m0 + wm * 32 + mi * 16 + lk * 4;
        #pragma unroll
        for (int ni = 0; ni < 4; ni++) {
            int n = n0 + wn * 64 + ni * 16 + lm;
            #pragma unroll
            for (int r = 0; r < 4; r++) {
                int row = rbase + r;
                if (row < M) {
                    float cv = acc[mi][ni][r] + bvv[ni];
                    if constexpr (RES) {
                        if constexpr (RESB) cv += bf2f(((const u16*)resid)[(size_t)row * 512 + n]);
                        else                cv += resid[(size_t)row * 512 + n];
                    }
                    if constexpr (OUTF) ((float*)Cv)[(size_t)row * Cst + n] = cv;
                    else                ((u16*)Cv)[(size_t)row * Cst + n] = f2bf(cv);
                }
            }
        }
    }
}

// ---------------- fused edge GEMM1 + NP-gather + b1 + LN*g+be + ReLU -> hidC (v4) ----------------
// 512 threads / 8 waves. BM=64 edges, N=512 full, K=128 (BK=32).
// LDS 48 KB (A 16KB | B 32KB; f32 C 16x512 = 32KB overlays B in epilogue) -> 3 blocks/CU,
// so the ~553-block chunk grid fits in ONE residency round (was 2 at 64KB).
__global__ __launch_bounds__(512, 4)
void g1ln_k(const u16* __restrict__ efb, const u16* __restrict__ WTe,
            const u16* __restrict__ NPp, const int* __restrict__ eids, const int* __restrict__ srcv,
            const int* __restrict__ Be, int ci, int cap,
            const float* __restrict__ b1, const float* __restrict__ g, const float* __restrict__ be,
            u16* __restrict__ outb)
{
    __shared__ u16 lds[24576];             // 48 KB
    u16* sA = lds;                         // [64][128] swizzled, 16 KB
    u16* sB = lds + 8192;                  // [512][32] swizzled, 32 KB
    float* sC = (float*)(lds + 8192);      // [16][512] f32, 32 KB (epilogue, overlays B)
    int b0 = Be[ci];
    int M = min(Be[ci + 1] - b0, cap);
    const int m0 = blockIdx.x * 64;
    if (m0 >= M) return;
    const int t = threadIdx.x;
    const int lane = t & 63;
    const int w = t >> 6;                  // 8 waves; wave owns col slice w*64
    const int lm = lane & 15, lk = lane >> 4;

    // stage whole A (64 rows x 128 k, ef gather, granule-swizzled): 1024 granules, 2/thread
    #pragma unroll
    for (int p = 0; p < 2; p++) {
        int slot = p * 512 + t;
        int row = slot >> 4, gph = slot & 15;
        int gsrc = (gph & 8) | ((gph & 7) ^ (row & 7));
        int eid = eids[b0 + min(m0 + row, M - 1)];
        gl_lds16(efb + (size_t)eid * 128 + gsrc * 8, sA + slot * 8);
    }

    f32x4 acc[4][4] = {};
    for (int ks = 0; ks < 4; ks++) {
        // stage B slice (512 n x 32 k): 2048 granules, 4/thread; 4-granule XOR by n&3
        #pragma unroll
        for (int p = 0; p < 4; p++) {
            int slot = p * 512 + t;
            int n = slot >> 2, cph = slot & 3;
            int csrc = cph ^ (n & 3);
            gl_lds16(WTe + (size_t)n * 128 + ks * 32 + csrc * 8, sB + slot * 8);
        }
        __syncthreads();
        bf16x8 av[4], bv[4];
        #pragma unroll
        for (int mi = 0; mi < 4; mi++) {
            int row = mi * 16 + lm;
            int gl = ks * 4 + lk;
            int gph = (gl & 8) | ((gl & 7) ^ (row & 7));
            av[mi] = *(const bf16x8*)(sA + row * 128 + gph * 8);
        }
        #pragma unroll
        for (int ni = 0; ni < 4; ni++) {
            int n = w * 64 + ni * 16 + lm;
            bv[ni] = *(const bf16x8*)(sB + n * 32 + (lk ^ (n & 3)) * 8);
        }
        #pragma unroll
        for (int mi = 0; mi < 4; mi++)
            #pragma unroll
            for (int ni = 0; ni < 4; ni++)
                acc[mi][ni] = __builtin_amdgcn_mfma_f32_16x16x32_bf16(av[mi], bv[ni], acc[mi][ni], 0, 0, 0);
        __syncthreads();
    }

    // epilogue: four 16-row slabs through f32 LDS (granule-of-4 XOR swizzle by row&7)
    for (int s = 0; s < 4; s++) {
        #pragma unroll
        for (int ni = 0; ni < 4; ni++) {
            int col = w * 64 + ni * 16 + lm;
            int c4 = col >> 2;
            #pragma unroll
            for (int r = 0; r < 4; r++) {
                int row_l = lk * 4 + r;
                int ph4 = (c4 & ~7) | ((c4 & 7) ^ (row_l & 7));
                sC[row_l * 512 + ph4 * 4 + (col & 3)] = acc[s][ni][r];
            }
        }
        __syncthreads();
        #pragma unroll
        for (int i = 0; i < 2; i++) {
            int row_l = w * 2 + i;
            int row_g = m0 + s * 16 + row_l;
            if (row_g < M) {
                int g0 = lane * 2, g1 = g0 + 1;
                int p0 = (g0 & ~7) | ((g0 & 7) ^ (row_l & 7));
                int p1 = (g1 & ~7) | ((g1 & 7) ^ (row_l & 7));
                f32x4 ca = *(const f32x4*)(sC + row_l * 512 + p0 * 4);
                f32x4 cb = *(const f32x4*)(sC + row_l * 512 + p1 * 4);
                int eid = eids[b0 + row_g];
                const u16* gp = NPp + (size_t)srcv[eid] * 1536 + lane * 8;
                short8 gv = *(const short8*)gp;
                float x[8]; float ss = 0.f, s2 = 0.f;
                #pragma unroll
                for (int j = 0; j < 4; j++) x[j] = ca[j] + bf2f((u16)gv[j]) + b1[lane * 8 + j];
                #pragma unroll
                for (int j = 4; j < 8; j++) x[j] = cb[j - 4] + bf2f((u16)gv[j]) + b1[lane * 8 + j];
                #pragma unroll
                for (int j = 0; j < 8; j++) { ss += x[j]; s2 += x[j] * x[j]; }
                #pragma unroll
                for (int o = 32; o > 0; o >>= 1) { ss += __shfl_xor(ss, o); s2 += __shfl_xor(s2, o); }
                float mu = ss * (1.f / 512.f);
                float inv = rsqrtf(s2 * (1.f / 512.f) - mu * mu + 1e-5f);
                short8 ov;
                #pragma unroll
                for (int j = 0; j < 8; j++) {
                    float y = (x[j] - mu) * inv * g[lane * 8 + j] + be[lane * 8 + j];
                    ov[j] = (short)f2bf(fmaxf(y, 0.f));
                }
                *(short8*)(outb + (size_t)row_g * 512 + lane * 8) = ov;
            }
        }
        __syncthreads();
    }
}

// ---------------- (x + b1) -> LayerNorm*g+be -> ReLU, in place, wave per row ----------------
__global__ __launch_bounds__(256)
void ln_relu_k(u16* __restrict__ hid, int hst,
               const float* __restrict__ b1, const float* __restrict__ g, const float* __restrict__ be,
               int M) {
    int wid = threadIdx.x >> 6, lane = threadIdx.x & 63;
    long r = (long)blockIdx.x * 4 + wid;
    if (r >= M) return;
    u16* p = hid + r * hst + lane * 8;
    short8 v = *(const short8*)p;
    float x[8]; float s = 0.f, s2 = 0.f;
    #pragma unroll
    for (int j = 0; j < 8; j++) x[j] = bf2f((u16)v[j]) + b1[lane * 8 + j];
    #pragma unroll
    for (int j = 0; j < 8; j++) { s += x[j]; s2 += x[j] * x[j]; }
    #pragma unroll
    for (int o = 32; o > 0; o >>= 1) { s += __shfl_xor(s, o); s2 += __shfl_xor(s2, o); }
    float mu = s * (1.f / 512.f);
    float inv = rsqrtf(s2 * (1.f / 512.f) - mu * mu + 1e-5f);
    short8 ov;
    #pragma unroll
    for (int j = 0; j < 8; j++) {
        float y = (x[j] - mu) * inv * g[lane * 8 + j] + be[lane * 8 + j];
        ov[j] = (short)f2bf(fmaxf(y, 0.f));
    }
    *(short8*)p = ov;
}

// ---------------- CSR build ----------------
__global__ void zero_k(int* a, int n) { int i = blockIdx.x * 256 + threadIdx.x; if (i < n) a[i] = 0; }
__global__ void count_k(const int* __restrict__ dst, int* __restrict__ counts) {
    int i = blockIdx.x * 256 + threadIdx.x;
    if (i < NE) atomicAdd(&counts[dst[i]], 1);
}
__global__ __launch_bounds__(1024)
void scan_k(const int* __restrict__ counts, int* __restrict__ offs) {
    __shared__ int part[1024];
    int t = threadIdx.x;
    const int chunk = (NN + 1023) / 1024;
    int lo = t * chunk; if (lo > NN) lo = NN;
    int hi = lo + chunk; if (hi > NN) hi = NN;
    int s = 0;
    for (int i = lo; i < hi; i++) s += counts[i];
    part[t] = s;
    __syncthreads();
    for (int o = 1; o < 1024; o <<= 1) {
        int v2 = 0;
        if (t >= o) v2 = part[t - o];
        __syncthreads();
        part[t] += v2;
        __syncthreads();
    }
    int base = (t > 0) ? part[t - 1] : 0;
    for (int i = lo; i < hi; i++) { offs[i] = base; base += counts[i]; }
    if (t == 1023) offs[NN] = part[1023];
}
__global__ void scatter_k(const int* __restrict__ dst, const int* __restrict__ offs,
                          int* __restrict__ cur, int* __restrict__ eids) {
    int i = blockIdx.x * 256 + threadIdx.x;
    if (i < NE) {
        int d = dst[i];
        int pos = atomicAdd(&cur[d], 1);
        eids[offs[d] + pos] = i;
    }
}
__global__ void bounds_k(const int* __restrict__ offs, int* __restrict__ Pn, int* __restrict__ Be,
                         int NC, int CEt) {
    int c = threadIdx.x;
    if (c > NC) return;
    int n;
    if (c == 0) n = 0;
    else if (c == NC) n = NN;
    else {
        int target = c * CEt;
        int lo = 0, hi = NN;
        while (lo < hi) { int mid = (lo + hi + 1) >> 1; if (offs[mid] <= target) lo = mid; else hi = mid - 1; }
        n = lo;
    }
    Pn[c] = n; Be[c] = offs[n];
}

// ---------------- per-node softmax stats over full logit array ----------------
__global__ __launch_bounds__(256)
void mxden_k(const float* __restrict__ lg, const int* __restrict__ offs,
             float* __restrict__ mx, float* __restrict__ den) {
    int wid = threadIdx.x >> 6, lane = threadIdx.x & 63;
    int n = blockIdx.x * 4 + wid;
    if (n >= NN) return;
    int lo = offs[n], hi = offs[n + 1];
    int head = lane & 15, j = lane >> 4;
    float m = -1e30f;
    for (int pe = lo + j; pe < hi; pe += 4)
        m = fmaxf(m, lg[(long)pe * 16 + head]);
    m = fmaxf(m, __shfl_xor(m, 16));
    m = fmaxf(m, __shfl_xor(m, 32));
    float d = 0.f;
    for (int pe = lo + j; pe < hi; pe += 4)
        d += __expf(lg[(long)pe * 16 + head] - m);
    d += __shfl_xor(d, 16);
    d += __shfl_xor(d, 32);
    if (j == 0) { mx[n * 16 + head] = m; den[n * 16 + head] = d; }
}

// ---------------- weighted V aggregation for nodes inside chunk ci, wave per node ----------------
__global__ __launch_bounds__(256)
void aggc_k(const float* __restrict__ lg, const u16* __restrict__ v,
            const int* __restrict__ offs, const float* __restrict__ mx, const float* __restrict__ den,
            const int* __restrict__ Pn, const int* __restrict__ Be, int ci, int cap,
            u16* __restrict__ agg) {
    int wid = threadIdx.x >> 6, lane = threadIdx.x & 63;
    int n = blockIdx.x * 4 + wid;
    if (n >= NN) return;
    if (n < Pn[ci] || n >= Pn[ci + 1]) return;
    int lo = offs[n], hi = offs[n + 1], b0 = Be[ci];
    int head = lane >> 2;
    float m = mx[n * 16 + head];
    float dv = den[n * 16 + head];
    float rn = (hi > lo) ? (1.f / dv) : 0.f;
    float acc[8] = {0, 0, 0, 0, 0, 0, 0, 0};
    for (int pe = lo; pe < hi; pe++) {
        int r = pe - b0;
        if (r >= cap) break;
        float wgt = __expf(lg[(long)pe * 16 + head] - m);
        short8 vv = *(const short8*)(v + (long)r * 512 + lane * 8);
        #pragma unroll
        for (int j = 0; j < 8; j++) acc[j] += wgt * bf2f((u16)vv[j]);
    }
    short8 ov;
    #pragma unroll
    for (int j = 0; j < 8; j++) ov[j] = (short)f2bf(acc[j] * rn);
    *(short8*)(agg + (long)n * 512 + lane * 8) = ov;
}

extern "C" void kernel_launch(void* const* d_in, const int* in_sizes, int n_in,
                              void* d_out, int out_size, void* d_ws, size_t ws_size,
                              hipStream_t stream) {
    const float* h     = (const float*)d_in[0];
    const float* efeat = (const float*)d_in[1];
    const int*   eidx  = (const int*)d_in[2];
    const int* src = eidx;
    const int* dst = eidx + NE;
    const float* hkW1 = (const float*)d_in[3];  const float* hkb1 = (const float*)d_in[4];
    const float* hkg  = (const float*)d_in[5];  const float* hkbe = (const float*)d_in[6];
    const float* hkW2 = (const float*)d_in[7];  const float* hkb2 = (const float*)d_in[8];
    const float* hvW1 = (const float*)d_in[9];  const float* hvb1 = (const float*)d_in[10];
    const float* hvg  = (const float*)d_in[11]; const float* hvbe = (const float*)d_in[12];
    const float* hvW2 = (const float*)d_in[13]; const float* hvb2 = (const float*)d_in[14];
    const float* hqW1 = (const float*)d_in[15]; const float* hqb1 = (const float*)d_in[16];
    const float* hqg  = (const float*)d_in[17]; const float* hqbe = (const float*)d_in[18];
    const float* hqW2 = (const float*)d_in[19]; const float* hqb2 = (const float*)d_in[20];
    const float* noW1 = (const float*)d_in[21]; const float* nob1 = (const float*)d_in[22];
    const float* nog  = (const float*)d_in[23]; const float* nobe = (const float*)d_in[24];
    const float* noW2 = (const float*)d_in[25]; const float* nob2 = (const float*)d_in[26];
    (void)in_sizes; (void)n_in; (void)out_size;

    char* wsp = (char*)d_ws;
    auto take = [&](size_t b) -> char* {
        char* r = wsp; wsp += (b + 255) & ~(size_t)255; return r;
    };
    u16* hb    = (u16*)take((size_t)NN * 512 * 2);
    u16* efb   = (u16*)take((size_t)NE * 128 * 2);
    u16* qb    = (u16*)take((size_t)NN * 512 * 2);    // q; reused as final-MLP hidden
    u16* aggb  = (u16*)take((size_t)NN * 512 * 2);
    u16* NP    = (u16*)take((size_t)NN * 1536 * 2);   // [q-hid | k-part | v-part] per node
    float* lgb = (float*)take((size_t)NE * 16 * 4);
    float* mxb = (float*)take((size_t)NN * 16 * 4);
    float* denb= (float*)take((size_t)NN * 16 * 4);
    u16* WTn    = (u16*)take((size_t)1536 * 512 * 2); // stacked [hqW1T | hkW1Th | hvW1Th]
    u16* noW1T  = (u16*)take(512 * 1024 * 2);
    u16* hkW1Te = (u16*)take(512 * 128 * 2);
    u16* hvW1Te = (u16*)take(512 * 128 * 2);
    u16* hkW2T  = (u16*)take(512 * 512 * 2);
    u16* hvW2T  = (u16*)take(512 * 512 * 2);
    u16* hqW2T  = (u16*)take(512 * 512 * 2);
    u16* noW2T  = (u16*)take(512 * 512 * 2);
    int* counts = (int*)take(NN * 4);
    int* offs   = (int*)take((NN + 1) * 4);
    int* cur    = (int*)take(NN * 4);
    int* eids   = (int*)take(NE * 4);
    int* Pn     = (int*)take(64 * 4);
    int* Bed    = (int*)take(64 * 4);

    size_t base = (size_t)(wsp - (char*)d_ws);
    const int ncs[15] = {1, 2, 3, 4, 5, 6, 8, 10, 13, 16, 20, 25, 32, 40, 50};
    int NC = 50;
    size_t cap = (size_t)((NE + 49) / 50) + 2048;
    for (int i = 0; i < 15; i++) {
        int nc = ncs[i];
        int cet = (NE + nc - 1) / nc;
        size_t c2 = (nc == 1) ? (size_t)NE : (size_t)cet + 2048;
        size_t buf = (c2 * 1024 + 255) & ~(size_t)255;
        if (base + 2 * buf <= ws_size) { NC = nc; cap = c2; break; }
    }
    size_t chunkbuf = (cap * 1024 + 255) & ~(size_t)255;
    u16* hidC = (u16*)take(chunkbuf);
    u16* kvC  = (u16*)take(chunkbuf);
    const int icap = (int)cap;
    const int CEt = (NE + NC - 1) / NC;

    cvt_k<<<((NN * 512 / 4) + 255) / 256, 256, 0, stream>>>(h, hb, (long)NN * 512);
    cvt_k<<<((NE * 128 / 4) + 255) / 256, 256, 0, stream>>>(efeat, efb, (long)NE * 128);

    dim3 tb(256);
    ttr_k<<<dim3(16, 16), tb, 0, stream>>>(hqW1, WTn, 512);
    ttr_k<<<dim3(16, 16), tb, 0, stream>>>(hkW1, WTn + 512 * 512, 512);
    ttr_k<<<dim3(16, 16), tb, 0, stream>>>(hvW1, WTn + 2 * 512 * 512, 512);
    ttr_k<<<dim3(4, 16),  tb, 0, stream>>>(hkW1 + 512 * 512, hkW1Te, 128);
    ttr_k<<<dim3(4, 16),  tb, 0, stream>>>(hvW1 + 512 * 512, hvW1Te, 128);
    ttr_k<<<dim3(32, 16), tb, 0, stream>>>(noW1, noW1T, 1024);
    ttr_k<<<dim3(16, 16), tb, 0, stream>>>(hkW2, hkW2T, 512);
    ttr_k<<<dim3(16, 16), tb, 0, stream>>>(hvW2, hvW2T, 512);
    ttr_k<<<dim3(16, 16), tb, 0, stream>>>(hqW2, hqW2T, 512);
    ttr_k<<<dim3(16, 16), tb, 0, stream>>>(noW2, noW2T, 512);

    zero_k<<<(NN + 255) / 256, 256, 0, stream>>>(counts, NN);
    zero_k<<<(NN + 255) / 256, 256, 0, stream>>>(cur, NN);
    count_k<<<(NE + 255) / 256, 256, 0, stream>>>(dst, counts);
    scan_k<<<1, 1024, 0, stream>>>(counts, offs);
    scatter_k<<<(NE + 255) / 256, 256, 0, stream>>>(dst, offs, cur, eids);
    bounds_k<<<1, 64, 0, stream>>>(offs, Pn, Bed, NC, CEt);

    dim3 gNP(12, (NN + 127) / 128);
    dim3 gNS(4, (NN + 63) / 64);
    dim3 gC(4, ((int)cap + 127) / 128);
    int lnN = (NN + 3) / 4;
    int g1b = ((int)cap + 63) / 64;

    // ---- fused node-side W1 GEMM: NP[20000,1536] = hb @ [hqW1 | hkW1h | hvW1h]
    gemm_k<0, false, false, false, false><<<gNP, 256, 0, stream>>>(
        hb, nullptr, nullptr, nullptr, 0, 0, WTn, nullptr, NP,
        nullptr, nullptr, nullptr, NN, 512, 512, 1536);

    // ---- q MLP tail
    ln_relu_k<<<lnN, 256, 0, stream>>>(NP, 1536, hqb1, hqg, hqbe, NN);
    gemmS_k<0, true, false, false, false><<<gNS, 256, 0, stream>>>(NP, nullptr, hqW2T, hqb2, nullptr, qb,
                                                                   NN, 512, 1536, 512);

    // ---- K phase: fused g1ln -> hidC; GEMM2+logits fused
    for (int c = 0; c < NC; c++) {
        g1ln_k<<<g1b, 512, 0, stream>>>(efb, hkW1Te, NP + 512, eids, src, Bed, c, icap,
                                        hkb1, hkg, hkbe, hidC);
        gemm_k<0, true, true, false, true><<<gC, 256, 0, stream>>>(
            hidC, nullptr, eids, Bed, c, icap, hkW2T, hkb2, nullptr,
            qb, dst, lgb, 0, 512, 512, 512);
    }

    mxden_k<<<lnN, 256, 0, stream>>>(lgb, offs, mxb, denb);

    // ---- V phase: fused g1ln -> hidC; v -> kvC; aggregate
    for (int c = 0; c < NC; c++) {
        g1ln_k<<<g1b, 512, 0, stream>>>(efb, hvW1Te, NP + 1024, eids, src, Bed, c, icap,
                                        hvb1, hvg, hvbe, hidC);
        gemm_k<0, true, true, false, false><<<gC, 256, 0, stream>>>(
            hidC, nullptr, nullptr, Bed, c, icap, hvW2T, hvb2, kvC,
            nullptr, nullptr, nullptr, 0, 512, 512, 512);
        aggc_k<<<lnN, 256, 0, stream>>>(lgb, kvC, offs, mxb, denb, Pn, Bed, c, icap, aggb);
    }

    // ---- node output MLP (concat A) + bf16 residual, f32 into d_out
    gemmS_k<2, false, false, false, false><<<gNS, 256, 0, stream>>>(aggb, hb, noW1T, nullptr, nullptr, qb,
                                                                    NN, 1024, 512, 512);
    ln_relu_k<<<lnN, 256, 0, stream>>>(qb, 512, nob1, nog, nobe, NN);
    gemmS_k<0, true, true, true, true><<<gNS, 256, 0, stream>>>(qb, nullptr, noW2T, nob2, (const float*)hb, d_out,
                                                                NN, 512, 512, 512);
}

// Round 12
// 680.336 us; speedup vs baseline: 1.1439x; 1.0503x over previous
//
#include <hip/hip_runtime.h>

#define NN 20000
#define NE 100000

typedef unsigned short u16;
typedef __bf16 bf16x8 __attribute__((ext_vector_type(8)));
typedef float f32x4 __attribute__((ext_vector_type(4)));
typedef short short8 __attribute__((ext_vector_type(8)));
typedef u16 u16x4 __attribute__((ext_vector_type(4)));

__device__ __forceinline__ float bf2f(u16 u) {
    union { unsigned int i; float f; } x; x.i = ((unsigned int)u) << 16; return x.f;
}
__device__ __forceinline__ u16 f2bf(float f) {
    union { float f; unsigned int i; } x; x.f = f;
    unsigned int r = x.i + 0x7FFFu + ((x.i >> 16) & 1u);
    return (u16)(r >> 16);
}

__device__ __forceinline__ void gl_lds16(const void* g, void* l) {
    __builtin_amdgcn_global_load_lds(
        (__attribute__((address_space(1))) const void*)g,
        (__attribute__((address_space(3))) void*)l, 16, 0, 0);
}

// bijective XCD-aware block swizzle (m204): each XCD gets a contiguous wgid range
__device__ __forceinline__ void xcd_swz(int& x, int& y) {
    int gx = gridDim.x;
    int nwg = gx * gridDim.y;
    int bid = blockIdx.y * gx + blockIdx.x;
    int q = nwg >> 3, r = nwg & 7;
    int xcd = bid & 7, idx = bid >> 3;
    int wg = (xcd < r ? xcd * (q + 1) : r * (q + 1) + (xcd - r) * q) + idx;
    x = wg % gx; y = wg / gx;
}

// ---------------- f32 -> bf16 bulk convert (4-wide) ----------------
__global__ void cvt_k(const float* __restrict__ in, u16* __restrict__ out, long n) {
    long i = ((long)blockIdx.x * 256 + threadIdx.x) * 4;
    if (i < n) {
        f32x4 v = *(const f32x4*)(in + i);
        u16x4 o;
        #pragma unroll
        for (int j = 0; j < 4; j++) o[j] = f2bf(v[j]);
        *(u16x4*)(out + i) = o;
    }
}

// ---------------- tiled transpose+convert: WT[n*Kr + k] = bf16(W[k*512 + n]) ----------------
__global__ __launch_bounds__(256)
void ttr_k(const float* __restrict__ W, u16* __restrict__ WT, int Kr) {
    __shared__ float tile[32][33];
    int k0 = blockIdx.x * 32, n0 = blockIdx.y * 32;
    int tx = threadIdx.x & 31, ty = threadIdx.x >> 5;   // 32 x 8
    #pragma unroll
    for (int i = 0; i < 4; i++)
        tile[ty + 8 * i][tx] = W[(size_t)(k0 + ty + 8 * i) * 512 + n0 + tx];
    __syncthreads();
    #pragma unroll
    for (int i = 0; i < 4; i++)
        WT[(size_t)(n0 + ty + 8 * i) * Kr + k0 + tx] = f2bf(tile[tx][ty + 8 * i]);
}

// ---------------- big GEMM: C[M,Nn] = A[M,K] @ WT^T (+bias), BM=128 BN=128 BK=64 ----------------
// XCD-swizzled grid. AK=0 plain (stride Ast); AK=2 [A|A2] K=1024; AK=3 ef-gather (row=eids[b0+r]*128, K=128).
// LOGIT: no C write; logits vs gathered q rows -> lgv (needs DEVM).
template<int AK, bool BIAS, bool DEVM, bool OUTF, bool LOGIT>
__global__ __launch_bounds__(256, 2)
void gemm_k(const u16* __restrict__ A, const u16* __restrict__ A2,
            const int* __restrict__ eids, const int* __restrict__ Be, int ci, int cap,
            const u16* __restrict__ WT, const float* __restrict__ bias,
            void* __restrict__ Cv,
            const u16* __restrict__ qbv, const int* __restrict__ dstv, float* __restrict__ lgv,
            int Mh, int K, int Ast, int Cst)
{
    __shared__ u16 smem[128 * 128];           // K-loop: sA | sB halves; LOGIT epilogue: q tile
    u16* sA = smem;
    u16* sB = smem + 128 * 64;
    int M = Mh, b0 = 0;
    if constexpr (DEVM) {
        b0 = Be[ci];
        M = min(Be[ci + 1] - b0, cap);
    }
    int bx, by;
    xcd_swz(bx, by);
    const int m0 = by * 128;
    if (m0 >= M) return;                    // uniform per block, before any barrier
    const int t = threadIdx.x;
    const int n0 = bx * 128;
    const int lane = t & 63;
    const int w = t >> 6;
    const int lrow = lane >> 3;             // 0..7 row within 8-row wave slab
    const int swz = ((lane & 7) ^ lrow) * 8;// pre-swizzled source chunk (elems)
    const int ldst = w * 512 + lane * 8;    // linear LDS dest (elems) within pass slab

    size_t abase[4];
    #pragma unroll
    for (int p = 0; p < 4; p++) {
        int row = min(m0 + p * 32 + w * 8 + lrow, M - 1);
        if constexpr (AK == 3)      abase[p] = (size_t)eids[b0 + row] * 128;
        else if constexpr (AK == 2) abase[p] = (size_t)row * 512;
        else                        abase[p] = (size_t)row * Ast;
    }
    const int wm = w >> 1, wn = w & 1;
    const int lm = lane & 15, lk = lane >> 4;
    const int swzr = lm & 7;                // row&7 for fragment-read deswizzle

    f32x4 acc[4][4] = {};

    for (int k0 = 0; k0 < K; k0 += 64) {
        #pragma unroll
        for (int p = 0; p < 4; p++) {
            const u16* g;
            if constexpr (AK == 2) {
                g = (k0 < 512) ? (A + abase[p] + k0 + swz) : (A2 + abase[p] + (k0 - 512) + swz);
            } else {
                g = A + abase[p] + k0 + swz;
            }
            gl_lds16(g, sA + p * 2048 + ldst);
        }
        #pragma unroll
        for (int p = 0; p < 4; p++)
            gl_lds16(WT + (size_t)(n0 + p * 32 + w * 8 + lrow) * K + k0 + swz, sB + p * 2048 + ldst);
        __syncthreads();

        bf16x8 av[2][4], bv[2][4];
        #pragma unroll
        for (int hf = 0; hf < 2; hf++) {
            #pragma unroll
            for (int mi = 0; mi < 4; mi++)
                av[hf][mi] = *(const bf16x8*)(sA + (wm * 64 + mi * 16 + lm) * 64 + (((hf * 4 + lk) ^ swzr) * 8));
            #pragma unroll
            for (int ni = 0; ni < 4; ni++)
                bv[hf][ni] = *(const bf16x8*)(sB + (wn * 64 + ni * 16 + lm) * 64 + (((hf * 4 + lk) ^ swzr) * 8));
        }
        #pragma unroll
        for (int hf = 0; hf < 2; hf++)
            #pragma unroll
            for (int mi = 0; mi < 4; mi++)
                #pragma unroll
                for (int ni = 0; ni < 4; ni++)
                    acc[mi][ni] = __builtin_amdgcn_mfma_f32_16x16x32_bf16(av[hf][mi], bv[hf][ni], acc[mi][ni], 0, 0, 0);
        __syncthreads();
    }

    float bvv[4];
    #pragma unroll
    for (int ni = 0; ni < 4; ni++) bvv[ni] = BIAS ? bias[n0 + wn * 64 + ni * 16 + lm] : 0.f;

    if constexpr (LOGIT) {
        // stage q[dst[e]] tile (128 rows x 128 cols, swizzled) into smem
        const int qrow = t >> 4;            // 0..15 within pass
        const int qc = t & 15;
        #pragma unroll
        for (int p = 0; p < 8; p++) {
            int row = p * 16 + qrow;
            int grow = min(m0 + row, M - 1);
            int e = eids[b0 + grow];
            const u16* g = qbv + (size_t)dstv[e] * 512 + n0 + ((qc ^ (row & 7)) << 3);
            gl_lds16(g, smem + p * 2048 + t * 8);
        }
        __syncthreads();
        #pragma unroll
        for (int mi = 0; mi < 4; mi++) {
            #pragma unroll
            for (int r = 0; r < 4; r++) {
                int rloc = wm * 64 + mi * 16 + lk * 4 + r;
                float h0 = 0.f, h1 = 0.f;
                #pragma unroll
                for (int ni = 0; ni < 4; ni++) {
                    int cloc = wn * 64 + ni * 16 + lm;
                    int addr = rloc * 128 + ((((cloc >> 3) ^ (rloc & 7)) << 3) | (cloc & 7));
                    float qv = bf2f(smem[addr]);
                    float pr = (acc[mi][ni][r] + bvv[ni]) * qv;
                    if (ni < 2) h0 += pr; else h1 += pr;
                }
                #pragma unroll
                for (int o = 1; o < 16; o <<= 1) { h0 += __shfl_xor(h0, o); h1 += __shfl_xor(h1, o); }
                int grow = m0 + rloc;
                if (lm == 0 && grow < M) {
                    int hbase = (n0 >> 5) + wn * 2;
                    lgv[(size_t)(b0 + grow) * 16 + hbase]     = h0 * 0.17677669529663687f;
                    lgv[(size_t)(b0 + grow) * 16 + hbase + 1] = h1 * 0.17677669529663687f;
                }
            }
        }
        return;
    }

    #pragma unroll
    for (int mi = 0; mi < 4; mi++) {
        int rbase = m0 + wm * 64 + mi * 16 + lk * 4;
        #pragma unroll
        for (int ni = 0; ni < 4; ni++) {
            int n = n0 + wn * 64 + ni * 16 + lm;
            #pragma unroll
            for (int r = 0; r < 4; r++) {
                int row = rbase + r;
                if (row < M) {
                    float cv = acc[mi][ni][r] + bvv[ni];
                    if constexpr (OUTF) ((float*)Cv)[(size_t)row * Cst + n] = cv;
                    else                ((u16*)Cv)[(size_t)row * Cst + n] = f2bf(cv);
                }
            }
        }
    }
}

// ---------------- small GEMM for node-side M=20000: BM=64 BN=128 BK=64, XCD-swizzled ----------------
template<int AK, bool BIAS, bool RES, bool OUTF, bool RESB>
__global__ __launch_bounds__(256, 3)
void gemmS_k(const u16* __restrict__ A, const u16* __restrict__ A2,
             const u16* __restrict__ WT, const float* __restrict__ bias,
             const float* __restrict__ resid, void* __restrict__ Cv,
             int M, int K, int Ast, int Cst)
{
    __shared__ u16 sA[64 * 64];
    __shared__ u16 sB[128 * 64];
    int bx, by;
    xcd_swz(bx, by);
    const int m0 = by * 64;
    if (m0 >= M) return;
    const int t = threadIdx.x;
    const int n0 = bx * 128;
    const int lane = t & 63;
    const int w = t >> 6;
    const int lrow = lane >> 3;
    const int swz = ((lane & 7) ^ lrow) * 8;
    const int ldst = w * 512 + lane * 8;

    size_t abase[2];
    #pragma unroll
    for (int p = 0; p < 2; p++) {
        int row = min(m0 + p * 32 + w * 8 + lrow, M - 1);
        if constexpr (AK == 2) abase[p] = (size_t)row * 512;
        else                   abase[p] = (size_t)row * Ast;
    }
    const int wm = w >> 1, wn = w & 1;
    const int lm = lane & 15, lk = lane >> 4;
    const int swzr = lm & 7;

    f32x4 acc[2][4] = {};

    for (int k0 = 0; k0 < K; k0 += 64) {
        #pragma unroll
        for (int p = 0; p < 2; p++) {
            const u16* g;
            if constexpr (AK == 2) {
                g = (k0 < 512) ? (A + abase[p] + k0 + swz) : (A2 + abase[p] + (k0 - 512) + swz);
            } else {
                g = A + abase[p] + k0 + swz;
            }
            gl_lds16(g, sA + p * 2048 + ldst);
        }
        #pragma unroll
        for (int p = 0; p < 4; p++)
            gl_lds16(WT + (size_t)(n0 + p * 32 + w * 8 + lrow) * K + k0 + swz, sB + p * 2048 + ldst);
        __syncthreads();

        bf16x8 av[2][2], bv[2][4];
        #pragma unroll
        for (int hf = 0; hf < 2; hf++) {
            #pragma unroll
            for (int mi = 0; mi < 2; mi++)
                av[hf][mi] = *(const bf16x8*)(sA + (wm * 32 + mi * 16 + lm) * 64 + (((hf * 4 + lk) ^ swzr) * 8));
            #pragma unroll
            for (int ni = 0; ni < 4; ni++)
                bv[hf][ni] = *(const bf16x8*)(sB + (wn * 64 + ni * 16 + lm) * 64 + (((hf * 4 + lk) ^ swzr) * 8));
        }
        #pragma unroll
        for (int hf = 0; hf < 2; hf++)
            #pragma unroll
            for (int mi = 0; mi < 2; mi++)
                #pragma unroll
                for (int ni = 0; ni < 4; ni++)
                    acc[mi][ni] = __builtin_amdgcn_mfma_f32_16x16x32_bf16(av[hf][mi], bv[hf][ni], acc[mi][ni], 0, 0, 0);
        __syncthreads();
    }

    float bvv[4];
    #pragma unroll
    for (int ni = 0; ni < 4; ni++) bvv[ni] = BIAS ? bias[n0 + wn * 64 + ni * 16 + lm] : 0.f;
    #pragma unroll
    for (int mi = 0; mi < 2; mi++) {
        int rbase = m0 + wm * 32 + mi * 16 + lk * 4;
        #pragma unroll
        for (int ni = 0; ni < 4; ni++) {
            int n = n0 + wn * 64 + ni * 16 + lm;
            #pragma unroll
            for (int r = 0; r < 4; r++) {
                int row = rbase + r;
                if (row < M) {
                    float cv = acc[mi][ni][r] + bvv[ni];
                    if constexpr (RES) {
                        if constexpr (RESB) cv += bf2f(((const u16*)resid)[(size_t)row * 512 + n]);
                        else                cv += resid[(size_t)row * 512 + n];
                    }
                    if constexpr (OUTF) ((float*)Cv)[(size_t)row * Cst + n] = cv;
                    else                ((u16*)Cv)[(size_t)row * Cst + n] = f2bf(cv);
                }
            }
        }
    }
}

// ---------------- (x + gathered NP row + b1) -> LayerNorm*g+be -> ReLU, in place, wave per row ----------------
__global__ __launch_bounds__(256)
void lnrg_k(u16* __restrict__ hid, const u16* __restrict__ gsrc,
            const int* __restrict__ eids, const int* __restrict__ srcv,
            const int* __restrict__ Be, int ci, int cap,
            const float* __restrict__ b1, const float* __restrict__ g, const float* __restrict__ be) {
    int b0 = Be[ci];
    int M = min(Be[ci + 1] - b0, cap);
    int wid = threadIdx.x >> 6, lane = threadIdx.x & 63;
    long r = (long)blockIdx.x * 4 + wid;
    if (r >= M) return;
    u16* p = hid + r * 512 + lane * 8;
    short8 v = *(const short8*)p;
    int eid = eids[b0 + r];
    const u16* gp = gsrc + (size_t)srcv[eid] * 1536 + lane * 8;
    short8 gv = *(const short8*)gp;
    float x[8]; float s = 0.f, s2 = 0.f;
    #pragma unroll
    for (int j = 0; j < 8; j++) x[j] = bf2f((u16)v[j]) + bf2f((u16)gv[j]) + b1[lane * 8 + j];
    #pragma unroll
    for (int j = 0; j < 8; j++) { s += x[j]; s2 += x[j] * x[j]; }
    #pragma unroll
    for (int o = 32; o > 0; o >>= 1) { s += __shfl_xor(s, o); s2 += __shfl_xor(s2, o); }
    float mu = s * (1.f / 512.f);
    float inv = rsqrtf(s2 * (1.f / 512.f) - mu * mu + 1e-5f);
    short8 ov;
    #pragma unroll
    for (int j = 0; j < 8; j++) {
        float y = (x[j] - mu) * inv * g[lane * 8 + j] + be[lane * 8 + j];
        ov[j] = (short)f2bf(fmaxf(y, 0.f));
    }
    *(short8*)p = ov;
}

// ---------------- (x + b1) -> LayerNorm*g+be -> ReLU, in place, wave per row ----------------
__global__ __launch_bounds__(256)
void ln_relu_k(u16* __restrict__ hid, int hst,
               const float* __restrict__ b1, const float* __restrict__ g, const float* __restrict__ be,
               int M) {
    int wid = threadIdx.x >> 6, lane = threadIdx.x & 63;
    long r = (long)blockIdx.x * 4 + wid;
    if (r >= M) return;
    u16* p = hid + r * hst + lane * 8;
    short8 v = *(const short8*)p;
    float x[8]; float s = 0.f, s2 = 0.f;
    #pragma unroll
    for (int j = 0; j < 8; j++) x[j] = bf2f((u16)v[j]) + b1[lane * 8 + j];
    #pragma unroll
    for (int j = 0; j < 8; j++) { s += x[j]; s2 += x[j] * x[j]; }
    #pragma unroll
    for (int o = 32; o > 0; o >>= 1) { s += __shfl_xor(s, o); s2 += __shfl_xor(s2, o); }
    float mu = s * (1.f / 512.f);
    float inv = rsqrtf(s2 * (1.f / 512.f) - mu * mu + 1e-5f);
    short8 ov;
    #pragma unroll
    for (int j = 0; j < 8; j++) {
        float y = (x[j] - mu) * inv * g[lane * 8 + j] + be[lane * 8 + j];
        ov[j] = (short)f2bf(fmaxf(y, 0.f));
    }
    *(short8*)p = ov;
}

// ---------------- CSR build ----------------
__global__ void zero_k(int* a, int n) { int i = blockIdx.x * 256 + threadIdx.x; if (i < n) a[i] = 0; }
__global__ void count_k(const int* __restrict__ dst, int* __restrict__ counts) {
    int i = blockIdx.x * 256 + threadIdx.x;
    if (i < NE) atomicAdd(&counts[dst[i]], 1);
}
__global__ __launch_bounds__(1024)
void scan_k(const int* __restrict__ counts, int* __restrict__ offs) {
    __shared__ int part[1024];
    int t = threadIdx.x;
    const int chunk = (NN + 1023) / 1024;
    int lo = t * chunk; if (lo > NN) lo = NN;
    int hi = lo + chunk; if (hi > NN) hi = NN;
    int s = 0;
    for (int i = lo; i < hi; i++) s += counts[i];
    part[t] = s;
    __syncthreads();
    for (int o = 1; o < 1024; o <<= 1) {
        int v2 = 0;
        if (t >= o) v2 = part[t - o];
        __syncthreads();
        part[t] += v2;
        __syncthreads();
    }
    int base = (t > 0) ? part[t - 1] : 0;
    for (int i = lo; i < hi; i++) { offs[i] = base; base += counts[i]; }
    if (t == 1023) offs[NN] = part[1023];
}
__global__ void scatter_k(const int* __restrict__ dst, const int* __restrict__ offs,
                          int* __restrict__ cur, int* __restrict__ eids) {
    int i = blockIdx.x * 256 + threadIdx.x;
    if (i < NE) {
        int d = dst[i];
        int pos = atomicAdd(&cur[d], 1);
        eids[offs[d] + pos] = i;
    }
}
__global__ void bounds_k(const int* __restrict__ offs, int* __restrict__ Pn, int* __restrict__ Be,
                         int NC, int CEt) {
    int c = threadIdx.x;
    if (c > NC) return;
    int n;
    if (c == 0) n = 0;
    else if (c == NC) n = NN;
    else {
        int target = c * CEt;
        int lo = 0, hi = NN;
        while (lo < hi) { int mid = (lo + hi + 1) >> 1; if (offs[mid] <= target) lo = mid; else hi = mid - 1; }
        n = lo;
    }
    Pn[c] = n; Be[c] = offs[n];
}

// ---------------- per-node softmax stats over full logit array ----------------
__global__ __launch_bounds__(256)
void mxden_k(const float* __restrict__ lg, const int* __restrict__ offs,
             float* __restrict__ mx, float* __restrict__ den) {
    int wid = threadIdx.x >> 6, lane = threadIdx.x & 63;
    int n = blockIdx.x * 4 + wid;
    if (n >= NN) return;
    int lo = offs[n], hi = offs[n + 1];
    int head = lane & 15, j = lane >> 4;
    float m = -1e30f;
    for (int pe = lo + j; pe < hi; pe += 4)
        m = fmaxf(m, lg[(long)pe * 16 + head]);
    m = fmaxf(m, __shfl_xor(m, 16));
    m = fmaxf(m, __shfl_xor(m, 32));
    float d = 0.f;
    for (int pe = lo + j; pe < hi; pe += 4)
        d += __expf(lg[(long)pe * 16 + head] - m);
    d += __shfl_xor(d, 16);
    d += __shfl_xor(d, 32);
    if (j == 0) { mx[n * 16 + head] = m; den[n * 16 + head] = d; }
}

// ---------------- weighted V aggregation for nodes inside chunk ci, wave per node ----------------
__global__ __launch_bounds__(256)
void aggc_k(const float* __restrict__ lg, const u16* __restrict__ v,
            const int* __restrict__ offs, const float* __restrict__ mx, const float* __restrict__ den,
            const int* __restrict__ Pn, const int* __restrict__ Be, int ci, int cap,
            u16* __restrict__ agg) {
    int wid = threadIdx.x >> 6, lane = threadIdx.x & 63;
    int n = blockIdx.x * 4 + wid;
    if (n >= NN) return;
    if (n < Pn[ci] || n >= Pn[ci + 1]) return;
    int lo = offs[n], hi = offs[n + 1], b0 = Be[ci];
    int head = lane >> 2;
    float m = mx[n * 16 + head];
    float dv = den[n * 16 + head];
    float rn = (hi > lo) ? (1.f / dv) : 0.f;
    float acc[8] = {0, 0, 0, 0, 0, 0, 0, 0};
    for (int pe = lo; pe < hi; pe++) {
        int r = pe - b0;
        if (r >= cap) break;
        float wgt = __expf(lg[(long)pe * 16 + head] - m);
        short8 vv = *(const short8*)(v + (long)r * 512 + lane * 8);
        #pragma unroll
        for (int j = 0; j < 8; j++) acc[j] += wgt * bf2f((u16)vv[j]);
    }
    short8 ov;
    #pragma unroll
    for (int j = 0; j < 8; j++) ov[j] = (short)f2bf(acc[j] * rn);
    *(short8*)(agg + (long)n * 512 + lane * 8) = ov;
}

extern "C" void kernel_launch(void* const* d_in, const int* in_sizes, int n_in,
                              void* d_out, int out_size, void* d_ws, size_t ws_size,
                              hipStream_t stream) {
    const float* h     = (const float*)d_in[0];
    const float* efeat = (const float*)d_in[1];
    const int*   eidx  = (const int*)d_in[2];
    const int* src = eidx;
    const int* dst = eidx + NE;
    const float* hkW1 = (const float*)d_in[3];  const float* hkb1 = (const float*)d_in[4];
    const float* hkg  = (const float*)d_in[5];  const float* hkbe = (const float*)d_in[6];
    const float* hkW2 = (const float*)d_in[7];  const float* hkb2 = (const float*)d_in[8];
    const float* hvW1 = (const float*)d_in[9];  const float* hvb1 = (const float*)d_in[10];
    const float* hvg  = (const float*)d_in[11]; const float* hvbe = (const float*)d_in[12];
    const float* hvW2 = (const float*)d_in[13]; const float* hvb2 = (const float*)d_in[14];
    const float* hqW1 = (const float*)d_in[15]; const float* hqb1 = (const float*)d_in[16];
    const float* hqg  = (const float*)d_in[17]; const float* hqbe = (const float*)d_in[18];
    const float* hqW2 = (const float*)d_in[19]; const float* hqb2 = (const float*)d_in[20];
    const float* noW1 = (const float*)d_in[21]; const float* nob1 = (const float*)d_in[22];
    const float* nog  = (const float*)d_in[23]; const float* nobe = (const float*)d_in[24];
    const float* noW2 = (const float*)d_in[25]; const float* nob2 = (const float*)d_in[26];
    (void)in_sizes; (void)n_in; (void)out_size;

    char* wsp = (char*)d_ws;
    auto take = [&](size_t b) -> char* {
        char* r = wsp; wsp += (b + 255) & ~(size_t)255; return r;
    };
    u16* hb    = (u16*)take((size_t)NN * 512 * 2);
    u16* efb   = (u16*)take((size_t)NE * 128 * 2);
    u16* qb    = (u16*)take((size_t)NN * 512 * 2);    // q; reused as final-MLP hidden
    u16* aggb  = (u16*)take((size_t)NN * 512 * 2);
    u16* NP    = (u16*)take((size_t)NN * 1536 * 2);   // [q-hid | k-part | v-part] per node
    float* lgb = (float*)take((size_t)NE * 16 * 4);
    float* mxb = (float*)take((size_t)NN * 16 * 4);
    float* denb= (float*)take((size_t)NN * 16 * 4);
    u16* WTn    = (u16*)take((size_t)1536 * 512 * 2); // stacked [hqW1T | hkW1Th | hvW1Th]
    u16* noW1T  = (u16*)take(512 * 1024 * 2);
    u16* hkW1Te = (u16*)take(512 * 128 * 2);
    u16* hvW1Te = (u16*)take(512 * 128 * 2);
    u16* hkW2T  = (u16*)take(512 * 512 * 2);
    u16* hvW2T  = (u16*)take(512 * 512 * 2);
    u16* hqW2T  = (u16*)take(512 * 512 * 2);
    u16* noW2T  = (u16*)take(512 * 512 * 2);
    int* counts = (int*)take(NN * 4);
    int* offs   = (int*)take((NN + 1) * 4);
    int* cur    = (int*)take(NN * 4);
    int* eids   = (int*)take(NE * 4);
    int* Pn     = (int*)take(64 * 4);
    int* Bed    = (int*)take(64 * 4);

    size_t base = (size_t)(wsp - (char*)d_ws);
    const int ncs[15] = {1, 2, 3, 4, 5, 6, 8, 10, 13, 16, 20, 25, 32, 40, 50};
    int NC = 50;
    size_t cap = (size_t)((NE + 49) / 50) + 2048;
    for (int i = 0; i < 15; i++) {
        int nc = ncs[i];
        int cet = (NE + nc - 1) / nc;
        size_t c2 = (nc == 1) ? (size_t)NE : (size_t)cet + 2048;
        size_t buf = (c2 * 1024 + 255) & ~(size_t)255;
        if (base + 2 * buf <= ws_size) { NC = nc; cap = c2; break; }
    }
    size_t chunkbuf = (cap * 1024 + 255) & ~(size_t)255;
    u16* hidC = (u16*)take(chunkbuf);
    u16* kvC  = (u16*)take(chunkbuf);
    const int icap = (int)cap;
    const int CEt = (NE + NC - 1) / NC;

    cvt_k<<<((NN * 512 / 4) + 255) / 256, 256, 0, stream>>>(h, hb, (long)NN * 512);
    cvt_k<<<((NE * 128 / 4) + 255) / 256, 256, 0, stream>>>(efeat, efb, (long)NE * 128);

    dim3 tb(256);
    ttr_k<<<dim3(16, 16), tb, 0, stream>>>(hqW1, WTn, 512);
    ttr_k<<<dim3(16, 16), tb, 0, stream>>>(hkW1, WTn + 512 * 512, 512);
    ttr_k<<<dim3(16, 16), tb, 0, stream>>>(hvW1, WTn + 2 * 512 * 512, 512);
    ttr_k<<<dim3(4, 16),  tb, 0, stream>>>(hkW1 + 512 * 512, hkW1Te, 128);
    ttr_k<<<dim3(4, 16),  tb, 0, stream>>>(hvW1 + 512 * 512, hvW1Te, 128);
    ttr_k<<<dim3(32, 16), tb, 0, stream>>>(noW1, noW1T, 1024);
    ttr_k<<<dim3(16, 16), tb, 0, stream>>>(hkW2, hkW2T, 512);
    ttr_k<<<dim3(16, 16), tb, 0, stream>>>(hvW2, hvW2T, 512);
    ttr_k<<<dim3(16, 16), tb, 0, stream>>>(hqW2, hqW2T, 512);
    ttr_k<<<dim3(16, 16), tb, 0, stream>>>(noW2, noW2T, 512);

    zero_k<<<(NN + 255) / 256, 256, 0, stream>>>(counts, NN);
    zero_k<<<(NN + 255) / 256, 256, 0, stream>>>(cur, NN);
    count_k<<<(NE + 255) / 256, 256, 0, stream>>>(dst, counts);
    scan_k<<<1, 1024, 0, stream>>>(counts, offs);
    scatter_k<<<(NE + 255) / 256, 256, 0, stream>>>(dst, offs, cur, eids);
    bounds_k<<<1, 64, 0, stream>>>(offs, Pn, Bed, NC, CEt);

    dim3 gNP(12, (NN + 127) / 128);
    dim3 gNS(4, (NN + 63) / 64);
    dim3 gC(4, ((int)cap + 127) / 128);
    int lnN = (NN + 3) / 4;
    int lnC = ((int)cap + 3) / 4;

    // ---- fused node-side W1 GEMM: NP[20000,1536] = hb @ [hqW1 | hkW1h | hvW1h]
    gemm_k<0, false, false, false, false><<<gNP, 256, 0, stream>>>(
        hb, nullptr, nullptr, nullptr, 0, 0, WTn, nullptr, NP,
        nullptr, nullptr, nullptr, NN, 512, 512, 1536);

    // ---- q MLP tail
    ln_relu_k<<<lnN, 256, 0, stream>>>(NP, 1536, hqb1, hqg, hqbe, NN);
    gemmS_k<0, true, false, false, false><<<gNS, 256, 0, stream>>>(NP, nullptr, hqW2T, hqb2, nullptr, qb,
                                                                   NN, 512, 1536, 512);

    // ---- K phase: ef-GEMM1 -> hidC; gather-LN in place; GEMM2+logits fused
    for (int c = 0; c < NC; c++) {
        gemm_k<3, false, true, false, false><<<gC, 256, 0, stream>>>(
            efb, nullptr, eids, Bed, c, icap, hkW1Te, nullptr, hidC,
            nullptr, nullptr, nullptr, 0, 128, 128, 512);
        lnrg_k<<<lnC, 256, 0, stream>>>(hidC, NP + 512, eids, src, Bed, c, icap, hkb1, hkg, hkbe);
        gemm_k<0, true, true, false, true><<<gC, 256, 0, stream>>>(
            hidC, nullptr, eids, Bed, c, icap, hkW2T, hkb2, nullptr,
            qb, dst, lgb, 0, 512, 512, 512);
    }

    mxden_k<<<lnN, 256, 0, stream>>>(lgb, offs, mxb, denb);

    // ---- V phase: ef-GEMM1 -> hidC; gather-LN; v -> kvC; aggregate
    for (int c = 0; c < NC; c++) {
        gemm_k<3, false, true, false, false><<<gC, 256, 0, stream>>>(
            efb, nullptr, eids, Bed, c, icap, hvW1Te, nullptr, hidC,
            nullptr, nullptr, nullptr, 0, 128, 128, 512);
        lnrg_k<<<lnC, 256, 0, stream>>>(hidC, NP + 1024, eids, src, Bed, c, icap, hvb1, hvg, hvbe);
        gemm_k<0, true, true, false, false><<<gC, 256, 0, stream>>>(
            hidC, nullptr, nullptr, Bed, c, icap, hvW2T, hvb2, kvC,
            nullptr, nullptr, nullptr, 0, 512, 512, 512);
        aggc_k<<<lnN, 256, 0, stream>>>(lgb, kvC, offs, mxb, denb, Pn, Bed, c, icap, aggb);
    }

    // ---- node output MLP (concat A) + bf16 residual, f32 into d_out
    gemmS_k<2, false, false, false, false><<<gNS, 256, 0, stream>>>(aggb, hb, noW1T, nullptr, nullptr, qb,
                                                                    NN, 1024, 512, 512);
    ln_relu_k<<<lnN, 256, 0, stream>>>(qb, 512, nob1, nog, nobe, NN);
    gemmS_k<0, true, true, true, true><<<gNS, 256, 0, stream>>>(qb, nullptr, noW2T, nob2, (const float*)hb, d_out,
                                                                NN, 512, 512, 512);
}

// Round 13
// 605.088 us; speedup vs baseline: 1.2862x; 1.1244x over previous
//
#include <hip/hip_runtime.h>

#define NN 20000
#define NE 100000

typedef unsigned short u16;
typedef __bf16 bf16x8 __attribute__((ext_vector_type(8)));
typedef float f32x4 __attribute__((ext_vector_type(4)));
typedef short short8 __attribute__((ext_vector_type(8)));
typedef u16 u16x4 __attribute__((ext_vector_type(4)));

__device__ __forceinline__ float bf2f(u16 u) {
    union { unsigned int i; float f; } x; x.i = ((unsigned int)u) << 16; return x.f;
}
__device__ __forceinline__ u16 f2bf(float f) {
    union { float f; unsigned int i; } x; x.f = f;
    unsigned int r = x.i + 0x7FFFu + ((x.i >> 16) & 1u);
    return (u16)(r >> 16);
}

__device__ __forceinline__ void gl_lds16(const void* g, void* l) {
    __builtin_amdgcn_global_load_lds(
        (__attribute__((address_space(1))) const void*)g,
        (__attribute__((address_space(3))) void*)l, 16, 0, 0);
}

// bijective XCD-aware block swizzle (m204)
__device__ __forceinline__ void xcd_swz(int& x, int& y) {
    int gx = gridDim.x;
    int nwg = gx * gridDim.y;
    int bid = blockIdx.y * gx + blockIdx.x;
    int q = nwg >> 3, r = nwg & 7;
    int xcd = bid & 7, idx = bid >> 3;
    int wg = (xcd < r ? xcd * (q + 1) : r * (q + 1) + (xcd - r) * q) + idx;
    x = wg % gx; y = wg / gx;
}

// ---------------- f32 -> bf16 bulk convert (4-wide) ----------------
__global__ void cvt_k(const float* __restrict__ in, u16* __restrict__ out, long n) {
    long i = ((long)blockIdx.x * 256 + threadIdx.x) * 4;
    if (i < n) {
        f32x4 v = *(const f32x4*)(in + i);
        u16x4 o;
        #pragma unroll
        for (int j = 0; j < 4; j++) o[j] = f2bf(v[j]);
        *(u16x4*)(out + i) = o;
    }
}

// ---------------- batched tiled transpose+convert: WT[n*Kr + k] = bf16(W[k*512 + n]) ----------------
struct TtrJobs { const float* W[8]; u16* WT[8]; };
__global__ __launch_bounds__(256)
void ttrb_k(TtrJobs jobs, int Kr) {
    __shared__ float tile[32][33];
    const float* W = jobs.W[blockIdx.z];
    u16* WT = jobs.WT[blockIdx.z];
    int k0 = blockIdx.x * 32, n0 = blockIdx.y * 32;
    int tx = threadIdx.x & 31, ty = threadIdx.x >> 5;   // 32 x 8
    #pragma unroll
    for (int i = 0; i < 4; i++)
        tile[ty + 8 * i][tx] = W[(size_t)(k0 + ty + 8 * i) * 512 + n0 + tx];
    __syncthreads();
    #pragma unroll
    for (int i = 0; i < 4; i++)
        WT[(size_t)(n0 + ty + 8 * i) * Kr + k0 + tx] = f2bf(tile[tx][ty + 8 * i]);
}

// ---------------- big GEMM: C[M,Nn] = A[M,K] @ WT^T (+bias), BM=128 BN=128 BK=64 ----------------
// XCD-swizzled grid. AK=0 plain (stride Ast); AK=2 [A|A2] K=1024; AK=3 ef-gather (row=eids[b0+r]*128, K=128).
// LOGIT: no C write; logits vs gathered q rows -> lgv (needs DEVM).
template<int AK, bool BIAS, bool DEVM, bool OUTF, bool LOGIT>
__global__ __launch_bounds__(256, 2)
void gemm_k(const u16* __restrict__ A, const u16* __restrict__ A2,
            const int* __restrict__ eids, const int* __restrict__ Be, int ci, int cap,
            const u16* __restrict__ WT, const float* __restrict__ bias,
            void* __restrict__ Cv,
            const u16* __restrict__ qbv, const int* __restrict__ dstv, float* __restrict__ lgv,
            int Mh, int K, int Ast, int Cst)
{
    __shared__ u16 smem[128 * 128];           // K-loop: sA | sB halves; LOGIT epilogue: q tile
    u16* sA = smem;
    u16* sB = smem + 128 * 64;
    int M = Mh, b0 = 0;
    if constexpr (DEVM) {
        b0 = Be[ci];
        M = min(Be[ci + 1] - b0, cap);
    }
    int bx, by;
    xcd_swz(bx, by);
    const int m0 = by * 128;
    if (m0 >= M) return;                    // uniform per block, before any barrier
    const int t = threadIdx.x;
    const int n0 = bx * 128;
    const int lane = t & 63;
    const int w = t >> 6;
    const int lrow = lane >> 3;             // 0..7 row within 8-row wave slab
    const int swz = ((lane & 7) ^ lrow) * 8;// pre-swizzled source chunk (elems)
    const int ldst = w * 512 + lane * 8;    // linear LDS dest (elems) within pass slab

    size_t abase[4];
    #pragma unroll
    for (int p = 0; p < 4; p++) {
        int row = min(m0 + p * 32 + w * 8 + lrow, M - 1);
        if constexpr (AK == 3)      abase[p] = (size_t)eids[b0 + row] * 128;
        else if constexpr (AK == 2) abase[p] = (size_t)row * 512;
        else                        abase[p] = (size_t)row * Ast;
    }
    const int wm = w >> 1, wn = w & 1;
    const int lm = lane & 15, lk = lane >> 4;
    const int swzr = lm & 7;                // row&7 for fragment-read deswizzle

    f32x4 acc[4][4] = {};

    for (int k0 = 0; k0 < K; k0 += 64) {
        #pragma unroll
        for (int p = 0; p < 4; p++) {
            const u16* g;
            if constexpr (AK == 2) {
                g = (k0 < 512) ? (A + abase[p] + k0 + swz) : (A2 + abase[p] + (k0 - 512) + swz);
            } else {
                g = A + abase[p] + k0 + swz;
            }
            gl_lds16(g, sA + p * 2048 + ldst);
        }
        #pragma unroll
        for (int p = 0; p < 4; p++)
            gl_lds16(WT + (size_t)(n0 + p * 32 + w * 8 + lrow) * K + k0 + swz, sB + p * 2048 + ldst);
        __syncthreads();

        bf16x8 av[2][4], bv[2][4];
        #pragma unroll
        for (int hf = 0; hf < 2; hf++) {
            #pragma unroll
            for (int mi = 0; mi < 4; mi++)
                av[hf][mi] = *(const bf16x8*)(sA + (wm * 64 + mi * 16 + lm) * 64 + (((hf * 4 + lk) ^ swzr) * 8));
            #pragma unroll
            for (int ni = 0; ni < 4; ni++)
                bv[hf][ni] = *(const bf16x8*)(sB + (wn * 64 + ni * 16 + lm) * 64 + (((hf * 4 + lk) ^ swzr) * 8));
        }
        #pragma unroll
        for (int hf = 0; hf < 2; hf++)
            #pragma unroll
            for (int mi = 0; mi < 4; mi++)
                #pragma unroll
                for (int ni = 0; ni < 4; ni++)
                    acc[mi][ni] = __builtin_amdgcn_mfma_f32_16x16x32_bf16(av[hf][mi], bv[hf][ni], acc[mi][ni], 0, 0, 0);
        __syncthreads();
    }

    float bvv[4];
    #pragma unroll
    for (int ni = 0; ni < 4; ni++) bvv[ni] = BIAS ? bias[n0 + wn * 64 + ni * 16 + lm] : 0.f;

    if constexpr (LOGIT) {
        // stage q[dst[e]] tile (128 rows x 128 cols, swizzled) into smem
        const int qrow = t >> 4;            // 0..15 within pass
        const int qc = t & 15;
        #pragma unroll
        for (int p = 0; p < 8; p++) {
            int row = p * 16 + qrow;
            int grow = min(m0 + row, M - 1);
            int e = eids[b0 + grow];
            const u16* g = qbv + (size_t)dstv[e] * 512 + n0 + ((qc ^ (row & 7)) << 3);
            gl_lds16(g, smem + p * 2048 + t * 8);
        }
        __syncthreads();
        #pragma unroll
        for (int mi = 0; mi < 4; mi++) {
            #pragma unroll
            for (int r = 0; r < 4; r++) {
                int rloc = wm * 64 + mi * 16 + lk * 4 + r;
                float h0 = 0.f, h1 = 0.f;
                #pragma unroll
                for (int ni = 0; ni < 4; ni++) {
                    int cloc = wn * 64 + ni * 16 + lm;
                    int addr = rloc * 128 + ((((cloc >> 3) ^ (rloc & 7)) << 3) | (cloc & 7));
                    float qv = bf2f(smem[addr]);
                    float pr = (acc[mi][ni][r] + bvv[ni]) * qv;
                    if (ni < 2) h0 += pr; else h1 += pr;
                }
                #pragma unroll
                for (int o = 1; o < 16; o <<= 1) { h0 += __shfl_xor(h0, o); h1 += __shfl_xor(h1, o); }
                int grow = m0 + rloc;
                if (lm == 0 && grow < M) {
                    int hbase = (n0 >> 5) + wn * 2;
                    lgv[(size_t)(b0 + grow) * 16 + hbase]     = h0 * 0.17677669529663687f;
                    lgv[(size_t)(b0 + grow) * 16 + hbase + 1] = h1 * 0.17677669529663687f;
                }
            }
        }
        return;
    }

    #pragma unroll
    for (int mi = 0; mi < 4; mi++) {
        int rbase = m0 + wm * 64 + mi * 16 + lk * 4;
        #pragma unroll
        for (int ni = 0; ni < 4; ni++) {
            int n = n0 + wn * 64 + ni * 16 + lm;
            #pragma unroll
            for (int r = 0; r < 4; r++) {
                int row = rbase + r;
                if (row < M) {
                    float cv = acc[mi][ni][r] + bvv[ni];
                    if constexpr (OUTF) ((float*)Cv)[(size_t)row * Cst + n] = cv;
                    else                ((u16*)Cv)[(size_t)row * Cst + n] = f2bf(cv);
                }
            }
        }
    }
}

// ---------------- small GEMM for node-side M=20000: BM=64 BN=128 BK=64, XCD-swizzled ----------------
template<int AK, bool BIAS, bool RES, bool OUTF, bool RESB>
__global__ __launch_bounds__(256, 3)
void gemmS_k(const u16* __restrict__ A, const u16* __restrict__ A2,
             const u16* __restrict__ WT, const float* __restrict__ bias,
             const float* __restrict__ resid, void* __restrict__ Cv,
             int M, int K, int Ast, int Cst)
{
    __shared__ u16 sA[64 * 64];
    __shared__ u16 sB[128 * 64];
    int bx, by;
    xcd_swz(bx, by);
    const int m0 = by * 64;
    if (m0 >= M) return;
    const int t = threadIdx.x;
    const int n0 = bx * 128;
    const int lane = t & 63;
    const int w = t >> 6;
    const int lrow = lane >> 3;
    const int swz = ((lane & 7) ^ lrow) * 8;
    const int ldst = w * 512 + lane * 8;

    size_t abase[2];
    #pragma unroll
    for (int p = 0; p < 2; p++) {
        int row = min(m0 + p * 32 + w * 8 + lrow, M - 1);
        if constexpr (AK == 2) abase[p] = (size_t)row * 512;
        else                   abase[p] = (size_t)row * Ast;
    }
    const int wm = w >> 1, wn = w & 1;
    const int lm = lane & 15, lk = lane >> 4;
    const int swzr = lm & 7;

    f32x4 acc[2][4] = {};

    for (int k0 = 0; k0 < K; k0 += 64) {
        #pragma unroll
        for (int p = 0; p < 2; p++) {
            const u16* g;
            if constexpr (AK == 2) {
                g = (k0 < 512) ? (A + abase[p] + k0 + swz) : (A2 + abase[p] + (k0 - 512) + swz);
            } else {
                g = A + abase[p] + k0 + swz;
            }
            gl_lds16(g, sA + p * 2048 + ldst);
        }
        #pragma unroll
        for (int p = 0; p < 4; p++)
            gl_lds16(WT + (size_t)(n0 + p * 32 + w * 8 + lrow) * K + k0 + swz, sB + p * 2048 + ldst);
        __syncthreads();

        bf16x8 av[2][2], bv[2][4];
        #pragma unroll
        for (int hf = 0; hf < 2; hf++) {
            #pragma unroll
            for (int mi = 0; mi < 2; mi++)
                av[hf][mi] = *(const bf16x8*)(sA + (wm * 32 + mi * 16 + lm) * 64 + (((hf * 4 + lk) ^ swzr) * 8));
            #pragma unroll
            for (int ni = 0; ni < 4; ni++)
                bv[hf][ni] = *(const bf16x8*)(sB + (wn * 64 + ni * 16 + lm) * 64 + (((hf * 4 + lk) ^ swzr) * 8));
        }
        #pragma unroll
        for (int hf = 0; hf < 2; hf++)
            #pragma unroll
            for (int mi = 0; mi < 2; mi++)
                #pragma unroll
                for (int ni = 0; ni < 4; ni++)
                    acc[mi][ni] = __builtin_amdgcn_mfma_f32_16x16x32_bf16(av[hf][mi], bv[hf][ni], acc[mi][ni], 0, 0, 0);
        __syncthreads();
    }

    float bvv[4];
    #pragma unroll
    for (int ni = 0; ni < 4; ni++) bvv[ni] = BIAS ? bias[n0 + wn * 64 + ni * 16 + lm] : 0.f;
    #pragma unroll
    for (int mi = 0; mi < 2; mi++) {
        int rbase = m0 + wm * 32 + mi * 16 + lk * 4;
        #pragma unroll
        for (int ni = 0; ni < 4; ni++) {
            int n = n0 + wn * 64 + ni * 16 + lm;
            #pragma unroll
            for (int r = 0; r < 4; r++) {
                int row = rbase + r;
                if (row < M) {
                    float cv = acc[mi][ni][r] + bvv[ni];
                    if constexpr (RES) {
                        if constexpr (RESB) cv += bf2f(((const u16*)resid)[(size_t)row * 512 + n]);
                        else                cv += resid[(size_t)row * 512 + n];
                    }
                    if constexpr (OUTF) ((float*)Cv)[(size_t)row * Cst + n] = cv;
                    else                ((u16*)Cv)[(size_t)row * Cst + n] = f2bf(cv);
                }
            }
        }
    }
}

// ---------------- (x + gathered NP row + b1) -> LayerNorm*g+be -> ReLU, in place, wave per row ----------------
__global__ __launch_bounds__(256)
void lnrg_k(u16* __restrict__ hid, const u16* __restrict__ gsrc, int gst,
            const int* __restrict__ eids, const int* __restrict__ srcv,
            const int* __restrict__ Be, int ci, int cap,
            const float* __restrict__ b1, const float* __restrict__ g, const float* __restrict__ be) {
    int b0 = Be[ci];
    int M = min(Be[ci + 1] - b0, cap);
    int wid = threadIdx.x >> 6, lane = threadIdx.x & 63;
    long r = (long)blockIdx.x * 4 + wid;
    if (r >= M) return;
    u16* p = hid + r * 512 + lane * 8;
    short8 v = *(const short8*)p;
    int eid = eids[b0 + r];
    const u16* gp = gsrc + (size_t)srcv[eid] * gst + lane * 8;
    short8 gv = *(const short8*)gp;
    float x[8]; float s = 0.f, s2 = 0.f;
    #pragma unroll
    for (int j = 0; j < 8; j++) x[j] = bf2f((u16)v[j]) + bf2f((u16)gv[j]) + b1[lane * 8 + j];
    #pragma unroll
    for (int j = 0; j < 8; j++) { s += x[j]; s2 += x[j] * x[j]; }
    #pragma unroll
    for (int o = 32; o > 0; o >>= 1) { s += __shfl_xor(s, o); s2 += __shfl_xor(s2, o); }
    float mu = s * (1.f / 512.f);
    float inv = rsqrtf(s2 * (1.f / 512.f) - mu * mu + 1e-5f);
    short8 ov;
    #pragma unroll
    for (int j = 0; j < 8; j++) {
        float y = (x[j] - mu) * inv * g[lane * 8 + j] + be[lane * 8 + j];
        ov[j] = (short)f2bf(fmaxf(y, 0.f));
    }
    *(short8*)p = ov;
}

// ---------------- (x + b1) -> LayerNorm*g+be -> ReLU, in place, wave per row ----------------
__global__ __launch_bounds__(256)
void ln_relu_k(u16* __restrict__ hid, int hst,
               const float* __restrict__ b1, const float* __restrict__ g, const float* __restrict__ be,
               int M) {
    int wid = threadIdx.x >> 6, lane = threadIdx.x & 63;
    long r = (long)blockIdx.x * 4 + wid;
    if (r >= M) return;
    u16* p = hid + r * hst + lane * 8;
    short8 v = *(const short8*)p;
    float x[8]; float s = 0.f, s2 = 0.f;
    #pragma unroll
    for (int j = 0; j < 8; j++) x[j] = bf2f((u16)v[j]) + b1[lane * 8 + j];
    #pragma unroll
    for (int j = 0; j < 8; j++) { s += x[j]; s2 += x[j] * x[j]; }
    #pragma unroll
    for (int o = 32; o > 0; o >>= 1) { s += __shfl_xor(s, o); s2 += __shfl_xor(s2, o); }
    float mu = s * (1.f / 512.f);
    float inv = rsqrtf(s2 * (1.f / 512.f) - mu * mu + 1e-5f);
    short8 ov;
    #pragma unroll
    for (int j = 0; j < 8; j++) {
        float y = (x[j] - mu) * inv * g[lane * 8 + j] + be[lane * 8 + j];
        ov[j] = (short)f2bf(fmaxf(y, 0.f));
    }
    *(short8*)p = ov;
}

// ---------------- CSR build ----------------
__global__ void zero2_k(int* a, int* b, int n) {
    int i = blockIdx.x * 256 + threadIdx.x;
    if (i < n) { a[i] = 0; b[i] = 0; }
}
__global__ void count_k(const int* __restrict__ dst, int* __restrict__ counts) {
    int i = blockIdx.x * 256 + threadIdx.x;
    if (i < NE) atomicAdd(&counts[dst[i]], 1);
}
__global__ __launch_bounds__(1024)
void scan_k(const int* __restrict__ counts, int* __restrict__ offs) {
    __shared__ int part[1024];
    int t = threadIdx.x;
    const int chunk = (NN + 1023) / 1024;
    int lo = t * chunk; if (lo > NN) lo = NN;
    int hi = lo + chunk; if (hi > NN) hi = NN;
    int s = 0;
    for (int i = lo; i < hi; i++) s += counts[i];
    part[t] = s;
    __syncthreads();
    for (int o = 1; o < 1024; o <<= 1) {
        int v2 = 0;
        if (t >= o) v2 = part[t - o];
        __syncthreads();
        part[t] += v2;
        __syncthreads();
    }
    int base = (t > 0) ? part[t - 1] : 0;
    for (int i = lo; i < hi; i++) { offs[i] = base; base += counts[i]; }
    if (t == 1023) offs[NN] = part[1023];
}
__global__ void scatter_k(const int* __restrict__ dst, const int* __restrict__ offs,
                          int* __restrict__ cur, int* __restrict__ eids) {
    int i = blockIdx.x * 256 + threadIdx.x;
    if (i < NE) {
        int d = dst[i];
        int pos = atomicAdd(&cur[d], 1);
        eids[offs[d] + pos] = i;
    }
}
__global__ void bounds_k(const int* __restrict__ offs, int* __restrict__ Pn, int* __restrict__ Be,
                         int NC, int CEt) {
    int c = threadIdx.x;
    if (c > NC) return;
    int n;
    if (c == 0) n = 0;
    else if (c == NC) n = NN;
    else {
        int target = c * CEt;
        int lo = 0, hi = NN;
        while (lo < hi) { int mid = (lo + hi + 1) >> 1; if (offs[mid] <= target) lo = mid; else hi = mid - 1; }
        n = lo;
    }
    Pn[c] = n; Be[c] = offs[n];
}

// ---------------- per-node softmax stats over full logit array ----------------
__global__ __launch_bounds__(256)
void mxden_k(const float* __restrict__ lg, const int* __restrict__ offs,
             float* __restrict__ mx, float* __restrict__ den) {
    int wid = threadIdx.x >> 6, lane = threadIdx.x & 63;
    int n = blockIdx.x * 4 + wid;
    if (n >= NN) return;
    int lo = offs[n], hi = offs[n + 1];
    int head = lane & 15, j = lane >> 4;
    float m = -1e30f;
    for (int pe = lo + j; pe < hi; pe += 4)
        m = fmaxf(m, lg[(long)pe * 16 + head]);
    m = fmaxf(m, __shfl_xor(m, 16));
    m = fmaxf(m, __shfl_xor(m, 32));
    float d = 0.f;
    for (int pe = lo + j; pe < hi; pe += 4)
        d += __expf(lg[(long)pe * 16 + head] - m);
    d += __shfl_xor(d, 16);
    d += __shfl_xor(d, 32);
    if (j == 0) { mx[n * 16 + head] = m; den[n * 16 + head] = d; }
}

// ---------------- weighted V aggregation for nodes inside chunk ci, wave per node ----------------
__global__ __launch_bounds__(256)
void aggc_k(const float* __restrict__ lg, const u16* __restrict__ v,
            const int* __restrict__ offs, const float* __restrict__ mx, const float* __restrict__ den,
            const int* __restrict__ Pn, const int* __restrict__ Be, int ci, int cap,
            u16* __restrict__ agg) {
    int wid = threadIdx.x >> 6, lane = threadIdx.x & 63;
    int n = blockIdx.x * 4 + wid;
    if (n >= NN) return;
    if (n < Pn[ci] || n >= Pn[ci + 1]) return;
    int lo = offs[n], hi = offs[n + 1], b0 = Be[ci];
    int head = lane >> 2;
    float m = mx[n * 16 + head];
    float dv = den[n * 16 + head];
    float rn = (hi > lo) ? (1.f / dv) : 0.f;
    float acc[8] = {0, 0, 0, 0, 0, 0, 0, 0};
    for (int pe = lo; pe < hi; pe++) {
        int r = pe - b0;
        if (r >= cap) break;
        float wgt = __expf(lg[(long)pe * 16 + head] - m);
        short8 vv = *(const short8*)(v + (long)r * 512 + lane * 8);
        #pragma unroll
        for (int j = 0; j < 8; j++) acc[j] += wgt * bf2f((u16)vv[j]);
    }
    short8 ov;
    #pragma unroll
    for (int j = 0; j < 8; j++) ov[j] = (short)f2bf(acc[j] * rn);
    *(short8*)(agg + (long)n * 512 + lane * 8) = ov;
}

extern "C" void kernel_launch(void* const* d_in, const int* in_sizes, int n_in,
                              void* d_out, int out_size, void* d_ws, size_t ws_size,
                              hipStream_t stream) {
    const float* h     = (const float*)d_in[0];
    const float* efeat = (const float*)d_in[1];
    const int*   eidx  = (const int*)d_in[2];
    const int* src = eidx;
    const int* dst = eidx + NE;
    const float* hkW1 = (const float*)d_in[3];  const float* hkb1 = (const float*)d_in[4];
    const float* hkg  = (const float*)d_in[5];  const float* hkbe = (const float*)d_in[6];
    const float* hkW2 = (const float*)d_in[7];  const float* hkb2 = (const float*)d_in[8];
    const float* hvW1 = (const float*)d_in[9];  const float* hvb1 = (const float*)d_in[10];
    const float* hvg  = (const float*)d_in[11]; const float* hvbe = (const float*)d_in[12];
    const float* hvW2 = (const float*)d_in[13]; const float* hvb2 = (const float*)d_in[14];
    const float* hqW1 = (const float*)d_in[15]; const float* hqb1 = (const float*)d_in[16];
    const float* hqg  = (const float*)d_in[17]; const float* hqbe = (const float*)d_in[18];
    const float* hqW2 = (const float*)d_in[19]; const float* hqb2 = (const float*)d_in[20];
    const float* noW1 = (const float*)d_in[21]; const float* nob1 = (const float*)d_in[22];
    const float* nog  = (const float*)d_in[23]; const float* nobe = (const float*)d_in[24];
    const float* noW2 = (const float*)d_in[25]; const float* nob2 = (const float*)d_in[26];
    (void)in_sizes; (void)n_in; (void)out_size;

    char* wsp = (char*)d_ws;
    auto take = [&](size_t b) -> char* {
        char* r = wsp; wsp += (b + 255) & ~(size_t)255; return r;
    };
    u16* hb    = (u16*)take((size_t)NN * 512 * 2);
    u16* efb   = (u16*)take((size_t)NE * 128 * 2);
    u16* qb    = (u16*)take((size_t)NN * 512 * 2);    // q; reused as final-MLP hidden
    u16* aggb  = (u16*)take((size_t)NN * 512 * 2);
    u16* NP    = (u16*)take((size_t)NN * 1024 * 2);   // [k-part | v-part] per node
    float* lgb = (float*)take((size_t)NE * 16 * 4);
    float* mxb = (float*)take((size_t)NN * 16 * 4);
    float* denb= (float*)take((size_t)NN * 16 * 4);
    u16* WTn    = (u16*)take((size_t)1024 * 512 * 2); // stacked [hkW1Th | hvW1Th]
    u16* hqW1T  = (u16*)take(512 * 512 * 2);
    u16* noW1T  = (u16*)take(512 * 1024 * 2);
    u16* hkW1Te = (u16*)take(512 * 128 * 2);
    u16* hvW1Te = (u16*)take(512 * 128 * 2);
    u16* hkW2T  = (u16*)take(512 * 512 * 2);
    u16* hvW2T  = (u16*)take(512 * 512 * 2);
    u16* hqW2T  = (u16*)take(512 * 512 * 2);
    u16* noW2T  = (u16*)take(512 * 512 * 2);
    int* counts = (int*)take(NN * 4);
    int* offs   = (int*)take((NN + 1) * 4);
    int* cur    = (int*)take(NN * 4);
    int* eids   = (int*)take(NE * 4);
    int* Pn     = (int*)take(64 * 4);
    int* Bed    = (int*)take(64 * 4);

    const size_t hidN_bytes = ((size_t)NN * 512 * 2 + 255) & ~(size_t)255;
    size_t base = (size_t)(wsp - (char*)d_ws);
    const int ncs[15] = {1, 2, 3, 4, 5, 6, 8, 10, 13, 16, 20, 25, 32, 40, 50};
    int NC = 50;
    size_t cap = (size_t)((NE + 49) / 50) + 2048;
    for (int i = 0; i < 15; i++) {
        int nc = ncs[i];
        int cet = (NE + nc - 1) / nc;
        size_t c2 = (nc == 1) ? (size_t)NE : (size_t)cet + 2048;
        size_t buf = (c2 * 1024 + 255) & ~(size_t)255;
        size_t region = (2 * buf > hidN_bytes) ? 2 * buf : hidN_bytes;
        if (base + region <= ws_size) { NC = nc; cap = c2; break; }
    }
    size_t chunkbuf = (cap * 1024 + 255) & ~(size_t)255;
    char* reg0 = take((2 * chunkbuf > hidN_bytes) ? 2 * chunkbuf : hidN_bytes);
    u16* hidN = (u16*)reg0;                 // q-hidden (dead once chunk loops start)
    u16* hidC = (u16*)reg0;
    u16* kvC  = (u16*)(reg0 + chunkbuf);
    const int icap = (int)cap;
    const int CEt = (NE + NC - 1) / NC;

    cvt_k<<<((NN * 512 / 4) + 255) / 256, 256, 0, stream>>>(h, hb, (long)NN * 512);
    cvt_k<<<((NE * 128 / 4) + 255) / 256, 256, 0, stream>>>(efeat, efb, (long)NE * 128);

    // batched weight transposes: Kr=512 group (7), Kr=128 group (2), Kr=1024 (1)
    {
        TtrJobs j{};
        j.W[0] = hqW1; j.WT[0] = hqW1T;
        j.W[1] = hkW1; j.WT[1] = WTn;                 // k-part rows 0..511
        j.W[2] = hvW1; j.WT[2] = WTn + 512 * 512;     // v-part rows 512..1023
        j.W[3] = hkW2; j.WT[3] = hkW2T;
        j.W[4] = hvW2; j.WT[4] = hvW2T;
        j.W[5] = hqW2; j.WT[5] = hqW2T;
        j.W[6] = noW2; j.WT[6] = noW2T;
        ttrb_k<<<dim3(16, 16, 7), 256, 0, stream>>>(j, 512);
        TtrJobs je{};
        je.W[0] = hkW1 + 512 * 512; je.WT[0] = hkW1Te;
        je.W[1] = hvW1 + 512 * 512; je.WT[1] = hvW1Te;
        ttrb_k<<<dim3(4, 16, 2), 256, 0, stream>>>(je, 128);
        TtrJobs jn{};
        jn.W[0] = noW1; jn.WT[0] = noW1T;
        ttrb_k<<<dim3(32, 16, 1), 256, 0, stream>>>(jn, 1024);
    }

    zero2_k<<<(NN + 255) / 256, 256, 0, stream>>>(counts, cur, NN);
    count_k<<<(NE + 255) / 256, 256, 0, stream>>>(dst, counts);
    scan_k<<<1, 1024, 0, stream>>>(counts, offs);
    scatter_k<<<(NE + 255) / 256, 256, 0, stream>>>(dst, offs, cur, eids);
    bounds_k<<<1, 64, 0, stream>>>(offs, Pn, Bed, NC, CEt);

    dim3 gNP(8, (NN + 127) / 128);
    dim3 gNQ(4, (NN + 127) / 128);
    dim3 gNS(4, (NN + 63) / 64);
    dim3 gC(4, ((int)cap + 127) / 128);
    int lnN = (NN + 3) / 4;
    int lnC = ((int)cap + 3) / 4;

    // ---- q MLP first (hidN aliases chunk region, consumed before chunk loops)
    gemm_k<0, false, false, false, false><<<gNQ, 256, 0, stream>>>(
        hb, nullptr, nullptr, nullptr, 0, 0, hqW1T, nullptr, hidN,
        nullptr, nullptr, nullptr, NN, 512, 512, 512);
    ln_relu_k<<<lnN, 256, 0, stream>>>(hidN, 512, hqb1, hqg, hqbe, NN);
    gemmS_k<0, true, false, false, false><<<gNS, 256, 0, stream>>>(hidN, nullptr, hqW2T, hqb2, nullptr, qb,
                                                                   NN, 512, 512, 512);

    // ---- node-side W1 GEMM for k/v: NP[20000,1024] = hb @ [hkW1h | hvW1h]
    gemm_k<0, false, false, false, false><<<gNP, 256, 0, stream>>>(
        hb, nullptr, nullptr, nullptr, 0, 0, WTn, nullptr, NP,
        nullptr, nullptr, nullptr, NN, 512, 512, 1024);

    // ---- K phase: ef-GEMM1 -> hidC; gather-LN in place; GEMM2+logits fused
    for (int c = 0; c < NC; c++) {
        gemm_k<3, false, true, false, false><<<gC, 256, 0, stream>>>(
            efb, nullptr, eids, Bed, c, icap, hkW1Te, nullptr, hidC,
            nullptr, nullptr, nullptr, 0, 128, 128, 512);
        lnrg_k<<<lnC, 256, 0, stream>>>(hidC, NP, 1024, eids, src, Bed, c, icap, hkb1, hkg, hkbe);
        gemm_k<0, true, true, false, true><<<gC, 256, 0, stream>>>(
            hidC, nullptr, eids, Bed, c, icap, hkW2T, hkb2, nullptr,
            qb, dst, lgb, 0, 512, 512, 512);
    }

    mxden_k<<<lnN, 256, 0, stream>>>(lgb, offs, mxb, denb);

    // ---- V phase: ef-GEMM1 -> hidC; gather-LN; v -> kvC; aggregate
    for (int c = 0; c < NC; c++) {
        gemm_k<3, false, true, false, false><<<gC, 256, 0, stream>>>(
            efb, nullptr, eids, Bed, c, icap, hvW1Te, nullptr, hidC,
            nullptr, nullptr, nullptr, 0, 128, 128, 512);
        lnrg_k<<<lnC, 256, 0, stream>>>(hidC, NP + 512, 1024, eids, src, Bed, c, icap, hvb1, hvg, hvbe);
        gemm_k<0, true, true, false, false><<<gC, 256, 0, stream>>>(
            hidC, nullptr, nullptr, Bed, c, icap, hvW2T, hvb2, kvC,
            nullptr, nullptr, nullptr, 0, 512, 512, 512);
        aggc_k<<<lnN, 256, 0, stream>>>(lgb, kvC, offs, mxb, denb, Pn, Bed, c, icap, aggb);
    }

    // ---- node output MLP (concat A) + bf16 residual, f32 into d_out
    gemmS_k<2, false, false, false, false><<<gNS, 256, 0, stream>>>(aggb, hb, noW1T, nullptr, nullptr, qb,
                                                                    NN, 1024, 512, 512);
    ln_relu_k<<<lnN, 256, 0, stream>>>(qb, 512, nob1, nog, nobe, NN);
    gemmS_k<0, true, true, true, true><<<gNS, 256, 0, stream>>>(qb, nullptr, noW2T, nob2, (const float*)hb, d_out,
                                                                NN, 512, 512, 512);
}

// Round 14
// 602.973 us; speedup vs baseline: 1.2907x; 1.0035x over previous
//
#include <hip/hip_runtime.h>

#define NN 20000
#define NE 100000

typedef unsigned short u16;
typedef __bf16 bf16x8 __attribute__((ext_vector_type(8)));
typedef float f32x4 __attribute__((ext_vector_type(4)));
typedef short short8 __attribute__((ext_vector_type(8)));
typedef u16 u16x4 __attribute__((ext_vector_type(4)));

__device__ __forceinline__ float bf2f(u16 u) {
    union { unsigned int i; float f; } x; x.i = ((unsigned int)u) << 16; return x.f;
}
__device__ __forceinline__ u16 f2bf(float f) {
    union { float f; unsigned int i; } x; x.f = f;
    unsigned int r = x.i + 0x7FFFu + ((x.i >> 16) & 1u);
    return (u16)(r >> 16);
}

__device__ __forceinline__ void gl_lds16(const void* g, void* l) {
    __builtin_amdgcn_global_load_lds(
        (__attribute__((address_space(1))) const void*)g,
        (__attribute__((address_space(3))) void*)l, 16, 0, 0);
}

// bijective XCD-aware block swizzle (m204)
__device__ __forceinline__ void xcd_swz(int& x, int& y) {
    int gx = gridDim.x;
    int nwg = gx * gridDim.y;
    int bid = blockIdx.y * gx + blockIdx.x;
    int q = nwg >> 3, r = nwg & 7;
    int xcd = bid & 7, idx = bid >> 3;
    int wg = (xcd < r ? xcd * (q + 1) : r * (q + 1) + (xcd - r) * q) + idx;
    x = wg % gx; y = wg / gx;
}

// ---------------- f32 -> bf16 bulk convert, two arrays in one launch ----------------
__global__ void cvt2_k(const float* __restrict__ a, u16* __restrict__ oa, long na,
                       const float* __restrict__ b, u16* __restrict__ ob, long nb) {
    long i = ((long)blockIdx.x * 256 + threadIdx.x) * 4;
    const float* in; u16* out;
    if (i < na) { in = a; out = oa; }
    else        { i -= na; in = b; out = ob; if (i >= nb) return; }
    f32x4 v = *(const f32x4*)(in + i);
    u16x4 o;
    #pragma unroll
    for (int j = 0; j < 4; j++) o[j] = f2bf(v[j]);
    *(u16x4*)(out + i) = o;
}

// ---------------- batched tiled transpose+convert: WT[n*Kr + k] = bf16(W[k*512 + n]) ----------------
struct TtrJobs { const float* W[8]; u16* WT[8]; };
__global__ __launch_bounds__(256)
void ttrb_k(TtrJobs jobs, int Kr) {
    __shared__ float tile[32][33];
    const float* W = jobs.W[blockIdx.z];
    u16* WT = jobs.WT[blockIdx.z];
    int k0 = blockIdx.x * 32, n0 = blockIdx.y * 32;
    int tx = threadIdx.x & 31, ty = threadIdx.x >> 5;   // 32 x 8
    #pragma unroll
    for (int i = 0; i < 4; i++)
        tile[ty + 8 * i][tx] = W[(size_t)(k0 + ty + 8 * i) * 512 + n0 + tx];
    __syncthreads();
    #pragma unroll
    for (int i = 0; i < 4; i++)
        WT[(size_t)(n0 + ty + 8 * i) * Kr + k0 + tx] = f2bf(tile[tx][ty + 8 * i]);
}

// ---------------- big GEMM: C[M,Nn] = A[M,K] @ WT^T (+bias), BM=128 BN=128 BK=64 ----------------
// XCD-swizzled grid. AK=0 plain (stride Ast); AK=2 [A|A2] K=1024; AK=3 ef-gather (row=eids[b0+r]*128, K=128).
// LOGIT: no C write; logits vs gathered q rows -> lgv (needs DEVM).
template<int AK, bool BIAS, bool DEVM, bool OUTF, bool LOGIT>
__global__ __launch_bounds__(256, 4)
void gemm_k(const u16* __restrict__ A, const u16* __restrict__ A2,
            const int* __restrict__ eids, const int* __restrict__ Be, int ci, int cap,
            const u16* __restrict__ WT, const float* __restrict__ bias,
            void* __restrict__ Cv,
            const u16* __restrict__ qbv, const int* __restrict__ dstv, float* __restrict__ lgv,
            int Mh, int K, int Ast, int Cst)
{
    __shared__ u16 smem[128 * 128];           // K-loop: sA | sB halves; LOGIT epilogue: q tile
    u16* sA = smem;
    u16* sB = smem + 128 * 64;
    int M = Mh, b0 = 0;
    if constexpr (DEVM) {
        b0 = Be[ci];
        M = min(Be[ci + 1] - b0, cap);
    }
    int bx, by;
    xcd_swz(bx, by);
    const int m0 = by * 128;
    if (m0 >= M) return;                    // uniform per block, before any barrier
    const int t = threadIdx.x;
    const int n0 = bx * 128;
    const int lane = t & 63;
    const int w = t >> 6;
    const int lrow = lane >> 3;             // 0..7 row within 8-row wave slab
    const int swz = ((lane & 7) ^ lrow) * 8;// pre-swizzled source chunk (elems)
    const int ldst = w * 512 + lane * 8;    // linear LDS dest (elems) within pass slab

    size_t abase[4];
    #pragma unroll
    for (int p = 0; p < 4; p++) {
        int row = min(m0 + p * 32 + w * 8 + lrow, M - 1);
        if constexpr (AK == 3)      abase[p] = (size_t)eids[b0 + row] * 128;
        else if constexpr (AK == 2) abase[p] = (size_t)row * 512;
        else                        abase[p] = (size_t)row * Ast;
    }
    const int wm = w >> 1, wn = w & 1;
    const int lm = lane & 15, lk = lane >> 4;
    const int swzr = lm & 7;                // row&7 for fragment-read deswizzle

    f32x4 acc[4][4] = {};

    for (int k0 = 0; k0 < K; k0 += 64) {
        #pragma unroll
        for (int p = 0; p < 4; p++) {
            const u16* g;
            if constexpr (AK == 2) {
                g = (k0 < 512) ? (A + abase[p] + k0 + swz) : (A2 + abase[p] + (k0 - 512) + swz);
            } else {
                g = A + abase[p] + k0 + swz;
            }
            gl_lds16(g, sA + p * 2048 + ldst);
        }
        #pragma unroll
        for (int p = 0; p < 4; p++)
            gl_lds16(WT + (size_t)(n0 + p * 32 + w * 8 + lrow) * K + k0 + swz, sB + p * 2048 + ldst);
        __syncthreads();

        bf16x8 av[2][4], bv[2][4];
        #pragma unroll
        for (int hf = 0; hf < 2; hf++) {
            #pragma unroll
            for (int mi = 0; mi < 4; mi++)
                av[hf][mi] = *(const bf16x8*)(sA + (wm * 64 + mi * 16 + lm) * 64 + (((hf * 4 + lk) ^ swzr) * 8));
            #pragma unroll
            for (int ni = 0; ni < 4; ni++)
                bv[hf][ni] = *(const bf16x8*)(sB + (wn * 64 + ni * 16 + lm) * 64 + (((hf * 4 + lk) ^ swzr) * 8));
        }
        #pragma unroll
        for (int hf = 0; hf < 2; hf++)
            #pragma unroll
            for (int mi = 0; mi < 4; mi++)
                #pragma unroll
                for (int ni = 0; ni < 4; ni++)
                    acc[mi][ni] = __builtin_amdgcn_mfma_f32_16x16x32_bf16(av[hf][mi], bv[hf][ni], acc[mi][ni], 0, 0, 0);
        __syncthreads();
    }

    float bvv[4];
    #pragma unroll
    for (int ni = 0; ni < 4; ni++) bvv[ni] = BIAS ? bias[n0 + wn * 64 + ni * 16 + lm] : 0.f;

    if constexpr (LOGIT) {
        // stage q[dst[e]] tile (128 rows x 128 cols, swizzled) into smem
        const int qrow = t >> 4;            // 0..15 within pass
        const int qc = t & 15;
        #pragma unroll
        for (int p = 0; p < 8; p++) {
            int row = p * 16 + qrow;
            int grow = min(m0 + row, M - 1);
            int e = eids[b0 + grow];
            const u16* g = qbv + (size_t)dstv[e] * 512 + n0 + ((qc ^ (row & 7)) << 3);
            gl_lds16(g, smem + p * 2048 + t * 8);
        }
        __syncthreads();
        #pragma unroll
        for (int mi = 0; mi < 4; mi++) {
            #pragma unroll
            for (int r = 0; r < 4; r++) {
                int rloc = wm * 64 + mi * 16 + lk * 4 + r;
                float h0 = 0.f, h1 = 0.f;
                #pragma unroll
                for (int ni = 0; ni < 4; ni++) {
                    int cloc = wn * 64 + ni * 16 + lm;
                    int addr = rloc * 128 + ((((cloc >> 3) ^ (rloc & 7)) << 3) | (cloc & 7));
                    float qv = bf2f(smem[addr]);
                    float pr = (acc[mi][ni][r] + bvv[ni]) * qv;
                    if (ni < 2) h0 += pr; else h1 += pr;
                }
                #pragma unroll
                for (int o = 1; o < 16; o <<= 1) { h0 += __shfl_xor(h0, o); h1 += __shfl_xor(h1, o); }
                int grow = m0 + rloc;
                if (lm == 0 && grow < M) {
                    int hbase = (n0 >> 5) + wn * 2;
                    lgv[(size_t)(b0 + grow) * 16 + hbase]     = h0 * 0.17677669529663687f;
                    lgv[(size_t)(b0 + grow) * 16 + hbase + 1] = h1 * 0.17677669529663687f;
                }
            }
        }
        return;
    }

    #pragma unroll
    for (int mi = 0; mi < 4; mi++) {
        int rbase = m0 + wm * 64 + mi * 16 + lk * 4;
        #pragma unroll
        for (int ni = 0; ni < 4; ni++) {
            int n = n0 + wn * 64 + ni * 16 + lm;
            #pragma unroll
            for (int r = 0; r < 4; r++) {
                int row = rbase + r;
                if (row < M) {
                    float cv = acc[mi][ni][r] + bvv[ni];
                    if constexpr (OUTF) ((float*)Cv)[(size_t)row * Cst + n] = cv;
                    else                ((u16*)Cv)[(size_t)row * Cst + n] = f2bf(cv);
                }
            }
        }
    }
}

// ---------------- small GEMM for node-side M=20000: BM=64 BN=128 BK=64, XCD-swizzled ----------------
template<int AK, bool BIAS, bool RES, bool OUTF, bool RESB>
__global__ __launch_bounds__(256, 6)
void gemmS_k(const u16* __restrict__ A, const u16* __restrict__ A2,
             const u16* __restrict__ WT, const float* __restrict__ bias,
             const float* __restrict__ resid, void* __restrict__ Cv,
             int M, int K, int Ast, int Cst)
{
    __shared__ u16 sA[64 * 64];
    __shared__ u16 sB[128 * 64];
    int bx, by;
    xcd_swz(bx, by);
    const int m0 = by * 64;
    if (m0 >= M) return;
    const int t = threadIdx.x;
    const int n0 = bx * 128;
    const int lane = t & 63;
    const int w = t >> 6;
    const int lrow = lane >> 3;
    const int swz = ((lane & 7) ^ lrow) * 8;
    const int ldst = w * 512 + lane * 8;

    size_t abase[2];
    #pragma unroll
    for (int p = 0; p < 2; p++) {
        int row = min(m0 + p * 32 + w * 8 + lrow, M - 1);
        if constexpr (AK == 2) abase[p] = (size_t)row * 512;
        else                   abase[p] = (size_t)row * Ast;
    }
    const int wm = w >> 1, wn = w & 1;
    const int lm = lane & 15, lk = lane >> 4;
    const int swzr = lm & 7;

    f32x4 acc[2][4] = {};

    for (int k0 = 0; k0 < K; k0 += 64) {
        #pragma unroll
        for (int p = 0; p < 2; p++) {
            const u16* g;
            if constexpr (AK == 2) {
                g = (k0 < 512) ? (A + abase[p] + k0 + swz) : (A2 + abase[p] + (k0 - 512) + swz);
            } else {
                g = A + abase[p] + k0 + swz;
            }
            gl_lds16(g, sA + p * 2048 + ldst);
        }
        #pragma unroll
        for (int p = 0; p < 4; p++)
            gl_lds16(WT + (size_t)(n0 + p * 32 + w * 8 + lrow) * K + k0 + swz, sB + p * 2048 + ldst);
        __syncthreads();

        bf16x8 av[2][2], bv[2][4];
        #pragma unroll
        for (int hf = 0; hf < 2; hf++) {
            #pragma unroll
            for (int mi = 0; mi < 2; mi++)
                av[hf][mi] = *(const bf16x8*)(sA + (wm * 32 + mi * 16 + lm) * 64 + (((hf * 4 + lk) ^ swzr) * 8));
            #pragma unroll
            for (int ni = 0; ni < 4; ni++)
                bv[hf][ni] = *(const bf16x8*)(sB + (wn * 64 + ni * 16 + lm) * 64 + (((hf * 4 + lk) ^ swzr) * 8));
        }
        #pragma unroll
        for (int hf = 0; hf < 2; hf++)
            #pragma unroll
            for (int mi = 0; mi < 2; mi++)
                #pragma unroll
                for (int ni = 0; ni < 4; ni++)
                    acc[mi][ni] = __builtin_amdgcn_mfma_f32_16x16x32_bf16(av[hf][mi], bv[hf][ni], acc[mi][ni], 0, 0, 0);
        __syncthreads();
    }

    float bvv[4];
    #pragma unroll
    for (int ni = 0; ni < 4; ni++) bvv[ni] = BIAS ? bias[n0 + wn * 64 + ni * 16 + lm] : 0.f;
    #pragma unroll
    for (int mi = 0; mi < 2; mi++) {
        int rbase = m0 + wm * 32 + mi * 16 + lk * 4;
        #pragma unroll
        for (int ni = 0; ni < 4; ni++) {
            int n = n0 + wn * 64 + ni * 16 + lm;
            #pragma unroll
            for (int r = 0; r < 4; r++) {
                int row = rbase + r;
                if (row < M) {
                    float cv = acc[mi][ni][r] + bvv[ni];
                    if constexpr (RES) {
                        if constexpr (RESB) cv += bf2f(((const u16*)resid)[(size_t)row * 512 + n]);
                        else                cv += resid[(size_t)row * 512 + n];
                    }
                    if constexpr (OUTF) ((float*)Cv)[(size_t)row * Cst + n] = cv;
                    else                ((u16*)Cv)[(size_t)row * Cst + n] = f2bf(cv);
                }
            }
        }
    }
}

// ---------------- (x + gathered NP row + b1) -> LayerNorm*g+be -> ReLU, in place, wave per row ----------------
__global__ __launch_bounds__(256)
void lnrg_k(u16* __restrict__ hid, const u16* __restrict__ gsrc, int gst,
            const int* __restrict__ eids, const int* __restrict__ srcv,
            const int* __restrict__ Be, int ci, int cap,
            const float* __restrict__ b1, const float* __restrict__ g, const float* __restrict__ be) {
    int b0 = Be[ci];
    int M = min(Be[ci + 1] - b0, cap);
    int wid = threadIdx.x >> 6, lane = threadIdx.x & 63;
    long r = (long)blockIdx.x * 4 + wid;
    if (r >= M) return;
    u16* p = hid + r * 512 + lane * 8;
    short8 v = *(const short8*)p;
    int eid = eids[b0 + r];
    const u16* gp = gsrc + (size_t)srcv[eid] * gst + lane * 8;
    short8 gv = *(const short8*)gp;
    float x[8]; float s = 0.f, s2 = 0.f;
    #pragma unroll
    for (int j = 0; j < 8; j++) x[j] = bf2f((u16)v[j]) + bf2f((u16)gv[j]) + b1[lane * 8 + j];
    #pragma unroll
    for (int j = 0; j < 8; j++) { s += x[j]; s2 += x[j] * x[j]; }
    #pragma unroll
    for (int o = 32; o > 0; o >>= 1) { s += __shfl_xor(s, o); s2 += __shfl_xor(s2, o); }
    float mu = s * (1.f / 512.f);
    float inv = rsqrtf(s2 * (1.f / 512.f) - mu * mu + 1e-5f);
    short8 ov;
    #pragma unroll
    for (int j = 0; j < 8; j++) {
        float y = (x[j] - mu) * inv * g[lane * 8 + j] + be[lane * 8 + j];
        ov[j] = (short)f2bf(fmaxf(y, 0.f));
    }
    *(short8*)p = ov;
}

// ---------------- (x + b1) -> LayerNorm*g+be -> ReLU, in place, wave per row ----------------
__global__ __launch_bounds__(256)
void ln_relu_k(u16* __restrict__ hid, int hst,
               const float* __restrict__ b1, const float* __restrict__ g, const float* __restrict__ be,
               int M) {
    int wid = threadIdx.x >> 6, lane = threadIdx.x & 63;
    long r = (long)blockIdx.x * 4 + wid;
    if (r >= M) return;
    u16* p = hid + r * hst + lane * 8;
    short8 v = *(const short8*)p;
    float x[8]; float s = 0.f, s2 = 0.f;
    #pragma unroll
    for (int j = 0; j < 8; j++) x[j] = bf2f((u16)v[j]) + b1[lane * 8 + j];
    #pragma unroll
    for (int j = 0; j < 8; j++) { s += x[j]; s2 += x[j] * x[j]; }
    #pragma unroll
    for (int o = 32; o > 0; o >>= 1) { s += __shfl_xor(s, o); s2 += __shfl_xor(s2, o); }
    float mu = s * (1.f / 512.f);
    float inv = rsqrtf(s2 * (1.f / 512.f) - mu * mu + 1e-5f);
    short8 ov;
    #pragma unroll
    for (int j = 0; j < 8; j++) {
        float y = (x[j] - mu) * inv * g[lane * 8 + j] + be[lane * 8 + j];
        ov[j] = (short)f2bf(fmaxf(y, 0.f));
    }
    *(short8*)p = ov;
}

// ---------------- CSR build ----------------
__global__ void zero2_k(int* a, int* b, int n) {
    int i = blockIdx.x * 256 + threadIdx.x;
    if (i < n) { a[i] = 0; b[i] = 0; }
}
__global__ void count_k(const int* __restrict__ dst, int* __restrict__ counts) {
    int i = blockIdx.x * 256 + threadIdx.x;
    if (i < NE) atomicAdd(&counts[dst[i]], 1);
}
__global__ __launch_bounds__(1024)
void scan_k(const int* __restrict__ counts, int* __restrict__ offs) {
    __shared__ int part[1024];
    int t = threadIdx.x;
    const int chunk = (NN + 1023) / 1024;
    int lo = t * chunk; if (lo > NN) lo = NN;
    int hi = lo + chunk; if (hi > NN) hi = NN;
    int s = 0;
    for (int i = lo; i < hi; i++) s += counts[i];
    part[t] = s;
    __syncthreads();
    for (int o = 1; o < 1024; o <<= 1) {
        int v2 = 0;
        if (t >= o) v2 = part[t - o];
        __syncthreads();
        part[t] += v2;
        __syncthreads();
    }
    int base = (t > 0) ? part[t - 1] : 0;
    for (int i = lo; i < hi; i++) { offs[i] = base; base += counts[i]; }
    if (t == 1023) offs[NN] = part[1023];
}
__global__ void scatter_k(const int* __restrict__ dst, const int* __restrict__ offs,
                          int* __restrict__ cur, int* __restrict__ eids) {
    int i = blockIdx.x * 256 + threadIdx.x;
    if (i < NE) {
        int d = dst[i];
        int pos = atomicAdd(&cur[d], 1);
        eids[offs[d] + pos] = i;
    }
}
__global__ void bounds_k(const int* __restrict__ offs, int* __restrict__ Pn, int* __restrict__ Be,
                         int NC, int CEt) {
    int c = threadIdx.x;
    if (c > NC) return;
    int n;
    if (c == 0) n = 0;
    else if (c == NC) n = NN;
    else {
        int target = c * CEt;
        int lo = 0, hi = NN;
        while (lo < hi) { int mid = (lo + hi + 1) >> 1; if (offs[mid] <= target) lo = mid; else hi = mid - 1; }
        n = lo;
    }
    Pn[c] = n; Be[c] = offs[n];
}

// ---------------- per-node softmax stats over full logit array ----------------
__global__ __launch_bounds__(256)
void mxden_k(const float* __restrict__ lg, const int* __restrict__ offs,
             float* __restrict__ mx, float* __restrict__ den) {
    int wid = threadIdx.x >> 6, lane = threadIdx.x & 63;
    int n = blockIdx.x * 4 + wid;
    if (n >= NN) return;
    int lo = offs[n], hi = offs[n + 1];
    int head = lane & 15, j = lane >> 4;
    float m = -1e30f;
    for (int pe = lo + j; pe < hi; pe += 4)
        m = fmaxf(m, lg[(long)pe * 16 + head]);
    m = fmaxf(m, __shfl_xor(m, 16));
    m = fmaxf(m, __shfl_xor(m, 32));
    float d = 0.f;
    for (int pe = lo + j; pe < hi; pe += 4)
        d += __expf(lg[(long)pe * 16 + head] - m);
    d += __shfl_xor(d, 16);
    d += __shfl_xor(d, 32);
    if (j == 0) { mx[n * 16 + head] = m; den[n * 16 + head] = d; }
}

// ---------------- weighted V aggregation for nodes inside chunk ci, wave per node ----------------
__global__ __launch_bounds__(256)
void aggc_k(const float* __restrict__ lg, const u16* __restrict__ v,
            const int* __restrict__ offs, const float* __restrict__ mx, const float* __restrict__ den,
            const int* __restrict__ Pn, const int* __restrict__ Be, int ci, int cap,
            u16* __restrict__ agg) {
    int wid = threadIdx.x >> 6, lane = threadIdx.x & 63;
    int n = blockIdx.x * 4 + wid;
    if (n >= NN) return;
    if (n < Pn[ci] || n >= Pn[ci + 1]) return;
    int lo = offs[n], hi = offs[n + 1], b0 = Be[ci];
    int head = lane >> 2;
    float m = mx[n * 16 + head];
    float dv = den[n * 16 + head];
    float rn = (hi > lo) ? (1.f / dv) : 0.f;
    float acc[8] = {0, 0, 0, 0, 0, 0, 0, 0};
    for (int pe = lo; pe < hi; pe++) {
        int r = pe - b0;
        if (r >= cap) break;
        float wgt = __expf(lg[(long)pe * 16 + head] - m);
        short8 vv = *(const short8*)(v + (long)r * 512 + lane * 8);
        #pragma unroll
        for (int j = 0; j < 8; j++) acc[j] += wgt * bf2f((u16)vv[j]);
    }
    short8 ov;
    #pragma unroll
    for (int j = 0; j < 8; j++) ov[j] = (short)f2bf(acc[j] * rn);
    *(short8*)(agg + (long)n * 512 + lane * 8) = ov;
}

extern "C" void kernel_launch(void* const* d_in, const int* in_sizes, int n_in,
                              void* d_out, int out_size, void* d_ws, size_t ws_size,
                              hipStream_t stream) {
    const float* h     = (const float*)d_in[0];
    const float* efeat = (const float*)d_in[1];
    const int*   eidx  = (const int*)d_in[2];
    const int* src = eidx;
    const int* dst = eidx + NE;
    const float* hkW1 = (const float*)d_in[3];  const float* hkb1 = (const float*)d_in[4];
    const float* hkg  = (const float*)d_in[5];  const float* hkbe = (const float*)d_in[6];
    const float* hkW2 = (const float*)d_in[7];  const float* hkb2 = (const float*)d_in[8];
    const float* hvW1 = (const float*)d_in[9];  const float* hvb1 = (const float*)d_in[10];
    const float* hvg  = (const float*)d_in[11]; const float* hvbe = (const float*)d_in[12];
    const float* hvW2 = (const float*)d_in[13]; const float* hvb2 = (const float*)d_in[14];
    const float* hqW1 = (const float*)d_in[15]; const float* hqb1 = (const float*)d_in[16];
    const float* hqg  = (const float*)d_in[17]; const float* hqbe = (const float*)d_in[18];
    const float* hqW2 = (const float*)d_in[19]; const float* hqb2 = (const float*)d_in[20];
    const float* noW1 = (const float*)d_in[21]; const float* nob1 = (const float*)d_in[22];
    const float* nog  = (const float*)d_in[23]; const float* nobe = (const float*)d_in[24];
    const float* noW2 = (const float*)d_in[25]; const float* nob2 = (const float*)d_in[26];
    (void)in_sizes; (void)n_in; (void)out_size;

    char* wsp = (char*)d_ws;
    auto take = [&](size_t b) -> char* {
        char* r = wsp; wsp += (b + 255) & ~(size_t)255; return r;
    };
    u16* hb    = (u16*)take((size_t)NN * 512 * 2);
    u16* efb   = (u16*)take((size_t)NE * 128 * 2);
    u16* qb    = (u16*)take((size_t)NN * 512 * 2);    // q; reused as final-MLP hidden
    u16* aggb  = (u16*)take((size_t)NN * 512 * 2);
    u16* NP    = (u16*)take((size_t)NN * 1024 * 2);   // [k-part | v-part] per node
    float* lgb = (float*)take((size_t)NE * 16 * 4);
    float* mxb = (float*)take((size_t)NN * 16 * 4);
    float* denb= (float*)take((size_t)NN * 16 * 4);
    u16* WTn    = (u16*)take((size_t)1024 * 512 * 2); // stacked [hkW1Th | hvW1Th]
    u16* hqW1T  = (u16*)take(512 * 512 * 2);
    u16* noW1T  = (u16*)take(512 * 1024 * 2);
    u16* hkW1Te = (u16*)take(512 * 128 * 2);
    u16* hvW1Te = (u16*)take(512 * 128 * 2);
    u16* hkW2T  = (u16*)take(512 * 512 * 2);
    u16* hvW2T  = (u16*)take(512 * 512 * 2);
    u16* hqW2T  = (u16*)take(512 * 512 * 2);
    u16* noW2T  = (u16*)take(512 * 512 * 2);
    int* counts = (int*)take(NN * 4);
    int* offs   = (int*)take((NN + 1) * 4);
    int* cur    = (int*)take(NN * 4);
    int* eids   = (int*)take(NE * 4);
    int* Pn     = (int*)take(64 * 4);
    int* Bed    = (int*)take(64 * 4);

    const size_t hidN_bytes = ((size_t)NN * 512 * 2 + 255) & ~(size_t)255;
    size_t base = (size_t)(wsp - (char*)d_ws);
    const int ncs[15] = {1, 2, 3, 4, 5, 6, 8, 10, 13, 16, 20, 25, 32, 40, 50};
    int NC = 50;
    size_t cap = (size_t)((NE + 49) / 50) + 2048;
    for (int i = 0; i < 15; i++) {
        int nc = ncs[i];
        int cet = (NE + nc - 1) / nc;
        size_t c2 = (nc == 1) ? (size_t)NE : (size_t)cet + 2048;
        size_t buf = (c2 * 1024 + 255) & ~(size_t)255;
        size_t region = (2 * buf > hidN_bytes) ? 2 * buf : hidN_bytes;
        if (base + region <= ws_size) { NC = nc; cap = c2; break; }
    }
    size_t chunkbuf = (cap * 1024 + 255) & ~(size_t)255;
    char* reg0 = take((2 * chunkbuf > hidN_bytes) ? 2 * chunkbuf : hidN_bytes);
    u16* hidN = (u16*)reg0;                 // q-hidden (dead once chunk loops start)
    u16* hidC = (u16*)reg0;
    u16* kvC  = (u16*)(reg0 + chunkbuf);
    const int icap = (int)cap;
    const int CEt = (NE + NC - 1) / NC;

    {
        long na = (long)NN * 512, nb = (long)NE * 128;
        long tot4 = (na + nb) / 4;
        cvt2_k<<<(int)((tot4 + 255) / 256), 256, 0, stream>>>(h, hb, na, efeat, efb, nb);
    }

    // batched weight transposes: Kr=512 group (7), Kr=128 group (2), Kr=1024 (1)
    {
        TtrJobs j{};
        j.W[0] = hqW1; j.WT[0] = hqW1T;
        j.W[1] = hkW1; j.WT[1] = WTn;                 // k-part rows 0..511
        j.W[2] = hvW1; j.WT[2] = WTn + 512 * 512;     // v-part rows 512..1023
        j.W[3] = hkW2; j.WT[3] = hkW2T;
        j.W[4] = hvW2; j.WT[4] = hvW2T;
        j.W[5] = hqW2; j.WT[5] = hqW2T;
        j.W[6] = noW2; j.WT[6] = noW2T;
        ttrb_k<<<dim3(16, 16, 7), 256, 0, stream>>>(j, 512);
        TtrJobs je{};
        je.W[0] = hkW1 + 512 * 512; je.WT[0] = hkW1Te;
        je.W[1] = hvW1 + 512 * 512; je.WT[1] = hvW1Te;
        ttrb_k<<<dim3(4, 16, 2), 256, 0, stream>>>(je, 128);
        TtrJobs jn{};
        jn.W[0] = noW1; jn.WT[0] = noW1T;
        ttrb_k<<<dim3(32, 16, 1), 256, 0, stream>>>(jn, 1024);
    }

    zero2_k<<<(NN + 255) / 256, 256, 0, stream>>>(counts, cur, NN);
    count_k<<<(NE + 255) / 256, 256, 0, stream>>>(dst, counts);
    scan_k<<<1, 1024, 0, stream>>>(counts, offs);
    scatter_k<<<(NE + 255) / 256, 256, 0, stream>>>(dst, offs, cur, eids);
    bounds_k<<<1, 64, 0, stream>>>(offs, Pn, Bed, NC, CEt);

    dim3 gNS(4, (NN + 63) / 64);
    dim3 gNS8(8, (NN + 63) / 64);
    dim3 gC(4, ((int)cap + 127) / 128);
    int lnN = (NN + 3) / 4;
    int lnC = ((int)cap + 3) / 4;

    // ---- q MLP first (hidN aliases chunk region, consumed before chunk loops)
    gemmS_k<0, false, false, false, false><<<gNS, 256, 0, stream>>>(hb, nullptr, hqW1T, nullptr, nullptr, hidN,
                                                                    NN, 512, 512, 512);
    ln_relu_k<<<lnN, 256, 0, stream>>>(hidN, 512, hqb1, hqg, hqbe, NN);
    gemmS_k<0, true, false, false, false><<<gNS, 256, 0, stream>>>(hidN, nullptr, hqW2T, hqb2, nullptr, qb,
                                                                   NN, 512, 512, 512);

    // ---- node-side W1 GEMM for k/v: NP[20000,1024] = hb @ [hkW1h | hvW1h]
    gemmS_k<0, false, false, false, false><<<gNS8, 256, 0, stream>>>(hb, nullptr, WTn, nullptr, nullptr, NP,
                                                                     NN, 512, 512, 1024);

    // ---- K phase: ef-GEMM1 -> hidC; gather-LN in place; GEMM2+logits fused
    for (int c = 0; c < NC; c++) {
        gemm_k<3, false, true, false, false><<<gC, 256, 0, stream>>>(
            efb, nullptr, eids, Bed, c, icap, hkW1Te, nullptr, hidC,
            nullptr, nullptr, nullptr, 0, 128, 128, 512);
        lnrg_k<<<lnC, 256, 0, stream>>>(hidC, NP, 1024, eids, src, Bed, c, icap, hkb1, hkg, hkbe);
        gemm_k<0, true, true, false, true><<<gC, 256, 0, stream>>>(
            hidC, nullptr, eids, Bed, c, icap, hkW2T, hkb2, nullptr,
            qb, dst, lgb, 0, 512, 512, 512);
    }

    mxden_k<<<lnN, 256, 0, stream>>>(lgb, offs, mxb, denb);

    // ---- V phase: ef-GEMM1 -> hidC; gather-LN; v -> kvC; aggregate
    for (int c = 0; c < NC; c++) {
        gemm_k<3, false, true, false, false><<<gC, 256, 0, stream>>>(
            efb, nullptr, eids, Bed, c, icap, hvW1Te, nullptr, hidC,
            nullptr, nullptr, nullptr, 0, 128, 128, 512);
        lnrg_k<<<lnC, 256, 0, stream>>>(hidC, NP + 512, 1024, eids, src, Bed, c, icap, hvb1, hvg, hvbe);
        gemm_k<0, true, true, false, false><<<gC, 256, 0, stream>>>(
            hidC, nullptr, nullptr, Bed, c, icap, hvW2T, hvb2, kvC,
            nullptr, nullptr, nullptr, 0, 512, 512, 512);
        aggc_k<<<lnN, 256, 0, stream>>>(lgb, kvC, offs, mxb, denb, Pn, Bed, c, icap, aggb);
    }

    // ---- node output MLP (concat A) + bf16 residual, f32 into d_out
    gemmS_k<2, false, false, false, false><<<gNS, 256, 0, stream>>>(aggb, hb, noW1T, nullptr, nullptr, qb,
                                                                    NN, 1024, 512, 512);
    ln_relu_k<<<lnN, 256, 0, stream>>>(qb, 512, nob1, nog, nobe, NN);
    gemmS_k<0, true, true, true, true><<<gNS, 256, 0, stream>>>(qb, nullptr, noW2T, nob2, (const float*)hb, d_out,
                                                                NN, 512, 512, 512);
}